// Round 1
// baseline (1108.592 us; speedup 1.0000x reference)
//
#include <hip/hip_runtime.h>
#include <hip/hip_bf16.h>
#include <cstddef>

#define IN_DIM 256
#define HID 128
#define OUT_DIM 40

// ---------------- CSR build ----------------

__global__ __launch_bounds__(256) void k_zero_deg(int* __restrict__ dout, int* __restrict__ din, int n) {
    int i = blockIdx.x * 256 + threadIdx.x;
    if (i < n) { dout[i] = 0; din[i] = 0; }
}

__global__ __launch_bounds__(256) void k_degrees(const int* __restrict__ src, const int* __restrict__ dst,
                                                 int* __restrict__ dout, int* __restrict__ din, int E) {
    int e = blockIdx.x * 256 + threadIdx.x;
    if (e < E) {
        atomicAdd(&dout[src[e]], 1);
        atomicAdd(&din[dst[e]], 1);
    }
}

__global__ __launch_bounds__(256) void k_scales(const int* __restrict__ dout, const int* __restrict__ din,
                                                float* __restrict__ rs_out, float* __restrict__ rs_in, int n) {
    int i = blockIdx.x * 256 + threadIdx.x;
    if (i < n) {
        rs_out[i] = rsqrtf((float)max(dout[i], 1));
        rs_in[i]  = rsqrtf((float)max(din[i], 1));
    }
}

// exclusive scan of deg_in -> row_ptr.  1024 items/block (256 thr x 4).
__global__ __launch_bounds__(256) void k_scan1(const int* __restrict__ deg, int* __restrict__ out,
                                               int* __restrict__ bsum, int n) {
    __shared__ int sd[256];
    int t = threadIdx.x, b = blockIdx.x;
    int base = b * 1024 + t * 4;
    int v0 = 0, v1 = 0, v2 = 0, v3 = 0;
    if (base + 0 < n) v0 = deg[base + 0];
    if (base + 1 < n) v1 = deg[base + 1];
    if (base + 2 < n) v2 = deg[base + 2];
    if (base + 3 < n) v3 = deg[base + 3];
    int ts = v0 + v1 + v2 + v3;
    sd[t] = ts;
    __syncthreads();
    for (int off = 1; off < 256; off <<= 1) {
        int x = 0;
        if (t >= off) x = sd[t - off];
        __syncthreads();
        sd[t] += x;
        __syncthreads();
    }
    int excl = sd[t] - ts;
    if (base + 0 < n) out[base + 0] = excl;
    if (base + 1 < n) out[base + 1] = excl + v0;
    if (base + 2 < n) out[base + 2] = excl + v0 + v1;
    if (base + 3 < n) out[base + 3] = excl + v0 + v1 + v2;
    if (t == 255) bsum[b] = sd[255];
}

__global__ __launch_bounds__(1024) void k_scan2(int* __restrict__ bsum, int nb) {
    __shared__ int sd[1024];
    int t = threadIdx.x;
    int v = (t < nb) ? bsum[t] : 0;
    sd[t] = v;
    __syncthreads();
    for (int off = 1; off < 1024; off <<= 1) {
        int x = 0;
        if (t >= off) x = sd[t - off];
        __syncthreads();
        sd[t] += x;
        __syncthreads();
    }
    if (t < nb) bsum[t] = sd[t] - v;   // exclusive
}

__global__ __launch_bounds__(256) void k_scan3(int* __restrict__ row_ptr, int* __restrict__ cursor,
                                               const int* __restrict__ bsum, int n, int E) {
    int i = blockIdx.x * 256 + threadIdx.x;
    if (i < n) {
        int v = row_ptr[i] + bsum[i >> 10];
        row_ptr[i] = v;
        cursor[i] = v;
    }
    if (i == 0) row_ptr[n] = E;
}

__global__ __launch_bounds__(256) void k_scatter(const int* __restrict__ src, const int* __restrict__ dst,
                                                 int* __restrict__ cursor, int* __restrict__ col, int E) {
    int e = blockIdx.x * 256 + threadIdx.x;
    if (e < E) {
        int d = dst[e];
        int pos = atomicAdd(&cursor[d], 1);
        col[pos] = src[e];
    }
}

// ---------------- GEMM1: h1 = (h @ W1) * rs_out[row]  (M x 256 @ 256 x 128) ----------------
// BM=64, BN=128(all), BK=16.  Thread: 4 rows (ty*4..+3) x 8 cols (tx*4..+3, tx*4+64..+67).
__global__ __launch_bounds__(256) void k_gemm1(const float* __restrict__ A, const float* __restrict__ B,
                                               const float* __restrict__ rs_out, float* __restrict__ C, int M) {
    __shared__ float As[16 * 68];    // [k][row], row dim padded 64->68 (2-way bank alias = free)
    __shared__ float Bs[16 * 128];   // [k][col]
    int t = threadIdx.x;
    int tx = t & 15, ty = t >> 4;
    int block_row = blockIdx.x * 64;
    int a_r = t >> 2;          // 0..63
    int a_k = (t & 3) * 4;     // 0,4,8,12
    float acc[4][8] = {};
    for (int k0 = 0; k0 < IN_DIM; k0 += 16) {
        int gr = block_row + a_r;
        float4 av = {0.f, 0.f, 0.f, 0.f};
        if (gr < M) av = *(const float4*)(A + (size_t)gr * IN_DIM + k0 + a_k);
        As[(a_k + 0) * 68 + a_r] = av.x;
        As[(a_k + 1) * 68 + a_r] = av.y;
        As[(a_k + 2) * 68 + a_r] = av.z;
        As[(a_k + 3) * 68 + a_r] = av.w;
#pragma unroll
        for (int i = 0; i < 2; ++i) {
            int u = t + i * 256;          // 512 float4 units
            int kb = u >> 5;
            int cu = (u & 31) * 4;
            *(float4*)&Bs[kb * 128 + cu] = *(const float4*)(B + (size_t)(k0 + kb) * HID + cu);
        }
        __syncthreads();
#pragma unroll
        for (int k = 0; k < 16; ++k) {
            float4 a  = *(const float4*)&As[k * 68 + ty * 4];
            float4 b0 = *(const float4*)&Bs[k * 128 + tx * 4];
            float4 b1 = *(const float4*)&Bs[k * 128 + tx * 4 + 64];
            float av4[4] = {a.x, a.y, a.z, a.w};
            float bv[8] = {b0.x, b0.y, b0.z, b0.w, b1.x, b1.y, b1.z, b1.w};
#pragma unroll
            for (int i = 0; i < 4; ++i)
#pragma unroll
                for (int j = 0; j < 8; ++j)
                    acc[i][j] = fmaf(av4[i], bv[j], acc[i][j]);
        }
        __syncthreads();
    }
#pragma unroll
    for (int i = 0; i < 4; ++i) {
        int r = block_row + ty * 4 + i;
        if (r >= M) continue;
        float sc = rs_out[r];
        float4 o0 = {acc[i][0] * sc, acc[i][1] * sc, acc[i][2] * sc, acc[i][3] * sc};
        float4 o1 = {acc[i][4] * sc, acc[i][5] * sc, acc[i][6] * sc, acc[i][7] * sc};
        *(float4*)(C + (size_t)r * HID + tx * 4) = o0;
        *(float4*)(C + (size_t)r * HID + tx * 4 + 64) = o1;
    }
}

// ---------------- SpMM1: x1[d] = relu(rs_in[d] * sum_{e in row d} h1[col[e]] + b1) ----------------
// one wave per dst node, float2 per lane (128 features)
__global__ __launch_bounds__(256) void k_spmm1(const float* __restrict__ h1, const int* __restrict__ rp,
                                               const int* __restrict__ col, const float* __restrict__ rs_in,
                                               const float* __restrict__ b1, float* __restrict__ x1, int n) {
    int w = (blockIdx.x * 256 + threadIdx.x) >> 6;
    int lane = threadIdx.x & 63;
    if (w >= n) return;
    int s = rp[w], e = rp[w + 1];
    const float2* hv = (const float2*)h1;
    float ax = 0.f, ay = 0.f;
    int i = s;
    for (; i + 4 <= e; i += 4) {
        int c0 = col[i], c1 = col[i + 1], c2 = col[i + 2], c3 = col[i + 3];
        float2 v0 = hv[(size_t)c0 * 64 + lane];
        float2 v1 = hv[(size_t)c1 * 64 + lane];
        float2 v2 = hv[(size_t)c2 * 64 + lane];
        float2 v3 = hv[(size_t)c3 * 64 + lane];
        ax += (v0.x + v1.x) + (v2.x + v3.x);
        ay += (v0.y + v1.y) + (v2.y + v3.y);
    }
    for (; i < e; ++i) {
        float2 v = hv[(size_t)col[i] * 64 + lane];
        ax += v.x; ay += v.y;
    }
    float sc = rs_in[w];
    float2 bb = ((const float2*)b1)[lane];
    float ox = fmaxf(fmaf(ax, sc, bb.x), 0.f);
    float oy = fmaxf(fmaf(ay, sc, bb.y), 0.f);
    ((float2*)x1)[(size_t)w * 64 + lane] = make_float2(ox, oy);
}

// ---------------- GEMM2: h2 = (x1 @ W2) * rs_out[row]  (M x 128 @ 128 x 40) ----------------
// BM=64 rows/block, thread: 2 rows x 5 cols, W2 staged transposed, float4 LDS reads.
__global__ __launch_bounds__(256) void k_gemm2(const float* __restrict__ A, const float* __restrict__ B,
                                               const float* __restrict__ rs_out, float* __restrict__ C, int M) {
    __shared__ float As[64 * 132];       // [row][k], k-pitch 132
    __shared__ float Wt[OUT_DIM * 132];  // [col][k]
    int t = threadIdx.x;
    int base_row = blockIdx.x * 64;
    // W2 [128][40] -> Wt[c][k]
    for (int i = 0; i < 20; ++i) {
        int flat = t + i * 256;          // 5120
        int k = flat / 40, c = flat - k * 40;
        Wt[c * 132 + k] = B[flat];
    }
    // A tile: 64 x 128, float4 units = 2048, 8/thread
#pragma unroll
    for (int i = 0; i < 8; ++i) {
        int u = t + i * 256;
        int row = u >> 5, kc = (u & 31) * 4;
        int gr = base_row + row;
        float4 v = {0.f, 0.f, 0.f, 0.f};
        if (gr < M) v = *(const float4*)(A + (size_t)gr * HID + kc);
        *(float4*)&As[row * 132 + kc] = v;
    }
    __syncthreads();
    int cg = t & 7, rg = t >> 3;
    int c0 = cg * 5, r0 = rg * 2;
    float acc[2][5] = {};
    for (int k = 0; k < HID; k += 4) {
        float4 a0 = *(const float4*)&As[r0 * 132 + k];
        float4 a1 = *(const float4*)&As[(r0 + 1) * 132 + k];
#pragma unroll
        for (int j = 0; j < 5; ++j) {
            float4 wv = *(const float4*)&Wt[(c0 + j) * 132 + k];
            acc[0][j] = fmaf(a0.x, wv.x, acc[0][j]);
            acc[0][j] = fmaf(a0.y, wv.y, acc[0][j]);
            acc[0][j] = fmaf(a0.z, wv.z, acc[0][j]);
            acc[0][j] = fmaf(a0.w, wv.w, acc[0][j]);
            acc[1][j] = fmaf(a1.x, wv.x, acc[1][j]);
            acc[1][j] = fmaf(a1.y, wv.y, acc[1][j]);
            acc[1][j] = fmaf(a1.z, wv.z, acc[1][j]);
            acc[1][j] = fmaf(a1.w, wv.w, acc[1][j]);
        }
    }
#pragma unroll
    for (int ri = 0; ri < 2; ++ri) {
        int r = base_row + r0 + ri;
        if (r < M) {
            float sc = rs_out[r];
#pragma unroll
            for (int j = 0; j < 5; ++j)
                C[(size_t)r * OUT_DIM + c0 + j] = acc[ri][j] * sc;
        }
    }
}

// ---------------- SpMM2 + bias + log_softmax ----------------
// one wave per dst node; lanes 0..39 = classes
__global__ __launch_bounds__(256) void k_spmm2(const float* __restrict__ h2, const int* __restrict__ rp,
                                               const int* __restrict__ col, const float* __restrict__ rs_in,
                                               const float* __restrict__ b2, float* __restrict__ out, int n) {
    int w = (blockIdx.x * 256 + threadIdx.x) >> 6;
    int lane = threadIdx.x & 63;
    if (w >= n) return;
    int f = (lane < OUT_DIM) ? lane : (OUT_DIM - 1);   // clamp: keep loads in-bounds, no divergence
    int s = rp[w], e = rp[w + 1];
    float acc = 0.f;
    int i = s;
    for (; i + 4 <= e; i += 4) {
        int c0 = col[i], c1 = col[i + 1], c2 = col[i + 2], c3 = col[i + 3];
        float v0 = h2[(size_t)c0 * OUT_DIM + f];
        float v1 = h2[(size_t)c1 * OUT_DIM + f];
        float v2 = h2[(size_t)c2 * OUT_DIM + f];
        float v3 = h2[(size_t)c3 * OUT_DIM + f];
        acc += (v0 + v1) + (v2 + v3);
    }
    for (; i < e; ++i) acc += h2[(size_t)col[i] * OUT_DIM + f];
    float v = fmaf(acc, rs_in[w], b2[f]);
    float vm = (lane < OUT_DIM) ? v : -INFINITY;
    for (int o = 32; o; o >>= 1) vm = fmaxf(vm, __shfl_xor(vm, o, 64));
    float ex = (lane < OUT_DIM) ? expf(v - vm) : 0.f;
    float sum = ex;
    for (int o = 32; o; o >>= 1) sum += __shfl_xor(sum, o, 64);
    if (lane < OUT_DIM) out[(size_t)w * OUT_DIM + lane] = v - vm - logf(sum);
}

// ---------------- launch ----------------

extern "C" void kernel_launch(void* const* d_in, const int* in_sizes, int n_in,
                              void* d_out, int out_size, void* d_ws, size_t ws_size,
                              hipStream_t stream) {
    const int N = in_sizes[0] / IN_DIM;
    const int E = in_sizes[5];
    const float* h  = (const float*)d_in[0];
    const float* W1 = (const float*)d_in[1];
    const float* b1 = (const float*)d_in[2];
    const float* W2 = (const float*)d_in[3];
    const float* b2 = (const float*)d_in[4];
    const int* src  = (const int*)d_in[5];
    const int* dst  = (const int*)d_in[6];
    float* out = (float*)d_out;

    char* w = (char*)d_ws;
    size_t off = 0;
    auto alloc = [&](size_t bytes) -> void* {
        void* p = w + off;
        off += (bytes + 255) & ~(size_t)255;
        return p;
    };
    int* deg_out  = (int*)alloc((size_t)N * 4);
    int* deg_in   = (int*)alloc((size_t)N * 4);
    int* row_ptr  = (int*)alloc((size_t)(N + 1) * 4);
    int* cursor   = (int*)alloc((size_t)N * 4);
    int* bsum     = (int*)alloc(1024 * 4);
    float* rs_out = (float*)alloc((size_t)N * 4);
    float* rs_in  = (float*)alloc((size_t)N * 4);
    int* col      = (int*)alloc((size_t)E * 4);
    float* h1     = (float*)alloc((size_t)N * HID * 4);
    float* x1     = (float*)alloc((size_t)N * HID * 4);
    float* h2     = h1;   // alias: h1 dead after spmm1 (saves 16 MB of ws)

    int gN = (N + 255) / 256;
    int gE = (E + 255) / 256;
    int NB = (N + 1023) / 1024;

    k_zero_deg<<<gN, 256, 0, stream>>>(deg_out, deg_in, N);
    k_degrees<<<gE, 256, 0, stream>>>(src, dst, deg_out, deg_in, E);
    k_scales<<<gN, 256, 0, stream>>>(deg_out, deg_in, rs_out, rs_in, N);
    k_scan1<<<NB, 256, 0, stream>>>(deg_in, row_ptr, bsum, N);
    k_scan2<<<1, 1024, 0, stream>>>(bsum, NB);
    k_scan3<<<gN, 256, 0, stream>>>(row_ptr, cursor, bsum, N, E);
    k_scatter<<<gE, 256, 0, stream>>>(src, dst, cursor, col, E);
    k_gemm1<<<(N + 63) / 64, 256, 0, stream>>>(h, W1, rs_out, h1, N);
    k_spmm1<<<(N + 3) / 4, 256, 0, stream>>>(h1, row_ptr, col, rs_in, b1, x1, N);
    k_gemm2<<<(N + 63) / 64, 256, 0, stream>>>(x1, W2, rs_out, h2, N);
    k_spmm2<<<(N + 3) / 4, 256, 0, stream>>>(h2, row_ptr, col, rs_in, b2, out, N);
}

// Round 2
// 890.147 us; speedup vs baseline: 1.2454x; 1.2454x over previous
//
#include <hip/hip_runtime.h>
#include <hip/hip_bf16.h>
#include <cstddef>
#include <cstdint>

#define IN_DIM 256
#define HID 128
#define OUT_DIM 40

#define CHUNK 16384     // edges per binscatter block (private staging region)
#define BIN_SHIFT 10    // 1024 nodes per bin
#define BIN_SIZE 1024
#define MAXB 128        // >= NBINS+1 (NBINS = ceil(100000/1024) = 98)

// ---------------- CSR build: chunk-private counting sort by dst/src bin ----------------
// Each block owns edges [j*CHUNK, j*CHUNK+nE) and staging region [j*CHUNK ...).
// Writes are private to the block -> L2-local -> full-line write-backs (no 15x amplification).
__global__ __launch_bounds__(256) void k_binscatter(const int* __restrict__ src, const int* __restrict__ dst,
                                                    uint32_t* __restrict__ stD, unsigned short* __restrict__ stS,
                                                    int* __restrict__ bboD, int* __restrict__ bboS,
                                                    int E, int NBINS) {
    __shared__ int hD[MAXB], hS[MAXB], cD[MAXB], cS[MAXB], sd[MAXB];
    int j = blockIdx.x, t = threadIdx.x;
    int base = j * CHUNK;
    int nE = min(CHUNK, E - base);
    int NB1 = NBINS + 1;
    for (int i = t; i < MAXB; i += 256) { hD[i] = 0; hS[i] = 0; }
    __syncthreads();
    for (int i = t; i < nE; i += 256) {
        atomicAdd(&hD[dst[base + i] >> BIN_SHIFT], 1);
        atomicAdd(&hS[src[base + i] >> BIN_SHIFT], 1);
    }
    __syncthreads();
    // scan hD -> cD (exclusive), emit bboD
    if (t < MAXB) sd[t] = hD[t];
    __syncthreads();
    for (int off = 1; off < MAXB; off <<= 1) {
        int x = 0;
        if (t < MAXB && t >= off) x = sd[t - off];
        __syncthreads();
        if (t < MAXB) sd[t] += x;
        __syncthreads();
    }
    if (t < MAXB) cD[t] = sd[t] - hD[t];
    if (t < NBINS) bboD[(size_t)j * NB1 + t] = sd[t] - hD[t];
    if (t == NBINS) bboD[(size_t)j * NB1 + NBINS] = nE;
    __syncthreads();
    // scan hS -> cS (exclusive), emit bboS
    if (t < MAXB) sd[t] = hS[t];
    __syncthreads();
    for (int off = 1; off < MAXB; off <<= 1) {
        int x = 0;
        if (t < MAXB && t >= off) x = sd[t - off];
        __syncthreads();
        if (t < MAXB) sd[t] += x;
        __syncthreads();
    }
    if (t < MAXB) cS[t] = sd[t] - hS[t];
    if (t < NBINS) bboS[(size_t)j * NB1 + t] = sd[t] - hS[t];
    if (t == NBINS) bboS[(size_t)j * NB1 + NBINS] = nE;
    __syncthreads();
    // scatter into private staging (re-read edges; chunk is L2-hot)
    for (int i = t; i < nE; i += 256) {
        int s = src[base + i], d = dst[base + i];
        int pD = atomicAdd(&cD[d >> BIN_SHIFT], 1);
        stD[(size_t)base + pD] = ((uint32_t)(d & (BIN_SIZE - 1)) << 17) | (uint32_t)s;
        int pS = atomicAdd(&cS[s >> BIN_SHIFT], 1);
        stS[(size_t)base + pS] = (unsigned short)(s & (BIN_SIZE - 1));
    }
}

// one block per dst-bin: histogram dst_local -> deg_in + rs_in (no global atomics)
__global__ __launch_bounds__(256) void k_deg_dst(const uint32_t* __restrict__ stD, const int* __restrict__ bboD,
                                                 int* __restrict__ deg_in, float* __restrict__ rs_in,
                                                 int N, int nchunk, int NBINS) {
    __shared__ int hist[BIN_SIZE];
    int b = blockIdx.x, t = threadIdx.x;
    int NB1 = NBINS + 1;
    for (int i = t; i < BIN_SIZE; i += 256) hist[i] = 0;
    __syncthreads();
    for (int j = 0; j < nchunk; ++j) {
        int s = bboD[(size_t)j * NB1 + b], e = bboD[(size_t)j * NB1 + b + 1];
        const uint32_t* seg = stD + (size_t)j * CHUNK;
        for (int i = s + t; i < e; i += 256)
            atomicAdd(&hist[seg[i] >> 17], 1);
    }
    __syncthreads();
    int base = b << BIN_SHIFT;
    for (int i = t; i < BIN_SIZE; i += 256) {
        int node = base + i;
        if (node < N) {
            int d = hist[i];
            deg_in[node] = d;
            rs_in[node] = rsqrtf((float)max(d, 1));
        }
    }
}

// one block per src-bin: histogram src_local -> rs_out
__global__ __launch_bounds__(256) void k_deg_src(const unsigned short* __restrict__ stS, const int* __restrict__ bboS,
                                                 float* __restrict__ rs_out, int N, int nchunk, int NBINS) {
    __shared__ int hist[BIN_SIZE];
    int b = blockIdx.x, t = threadIdx.x;
    int NB1 = NBINS + 1;
    for (int i = t; i < BIN_SIZE; i += 256) hist[i] = 0;
    __syncthreads();
    for (int j = 0; j < nchunk; ++j) {
        int s = bboS[(size_t)j * NB1 + b], e = bboS[(size_t)j * NB1 + b + 1];
        const unsigned short* seg = stS + (size_t)j * CHUNK;
        for (int i = s + t; i < e; i += 256)
            atomicAdd(&hist[seg[i]], 1);
    }
    __syncthreads();
    int base = b << BIN_SHIFT;
    for (int i = t; i < BIN_SIZE; i += 256) {
        int node = base + i;
        if (node < N) rs_out[node] = rsqrtf((float)max(hist[i], 1));
    }
}

// one block per dst-bin: LDS cursors from row_ptr, write col into the bin's contiguous window
__global__ __launch_bounds__(256) void k_col(const uint32_t* __restrict__ stD, const int* __restrict__ bboD,
                                             const int* __restrict__ row_ptr, int* __restrict__ col,
                                             int N, int nchunk, int NBINS) {
    __shared__ int cur[BIN_SIZE];
    int b = blockIdx.x, t = threadIdx.x;
    int NB1 = NBINS + 1;
    int base = b << BIN_SHIFT;
    for (int i = t; i < BIN_SIZE; i += 256) {
        int node = base + i;
        cur[i] = (node < N) ? row_ptr[node] : 0;
    }
    __syncthreads();
    for (int j = 0; j < nchunk; ++j) {
        int s = bboD[(size_t)j * NB1 + b], e = bboD[(size_t)j * NB1 + b + 1];
        const uint32_t* seg = stD + (size_t)j * CHUNK;
        for (int i = s + t; i < e; i += 256) {
            uint32_t v = seg[i];
            int pos = atomicAdd(&cur[v >> 17], 1);
            col[pos] = (int)(v & 0x1FFFFu);
        }
    }
}

// exclusive scan of deg_in -> row_ptr.  1024 items/block (256 thr x 4).
__global__ __launch_bounds__(256) void k_scan1(const int* __restrict__ deg, int* __restrict__ out,
                                               int* __restrict__ bsum, int n) {
    __shared__ int sd[256];
    int t = threadIdx.x, b = blockIdx.x;
    int base = b * 1024 + t * 4;
    int v0 = 0, v1 = 0, v2 = 0, v3 = 0;
    if (base + 0 < n) v0 = deg[base + 0];
    if (base + 1 < n) v1 = deg[base + 1];
    if (base + 2 < n) v2 = deg[base + 2];
    if (base + 3 < n) v3 = deg[base + 3];
    int ts = v0 + v1 + v2 + v3;
    sd[t] = ts;
    __syncthreads();
    for (int off = 1; off < 256; off <<= 1) {
        int x = 0;
        if (t >= off) x = sd[t - off];
        __syncthreads();
        sd[t] += x;
        __syncthreads();
    }
    int excl = sd[t] - ts;
    if (base + 0 < n) out[base + 0] = excl;
    if (base + 1 < n) out[base + 1] = excl + v0;
    if (base + 2 < n) out[base + 2] = excl + v0 + v1;
    if (base + 3 < n) out[base + 3] = excl + v0 + v1 + v2;
    if (t == 255) bsum[b] = sd[255];
}

__global__ __launch_bounds__(1024) void k_scan2(int* __restrict__ bsum, int nb) {
    __shared__ int sd[1024];
    int t = threadIdx.x;
    int v = (t < nb) ? bsum[t] : 0;
    sd[t] = v;
    __syncthreads();
    for (int off = 1; off < 1024; off <<= 1) {
        int x = 0;
        if (t >= off) x = sd[t - off];
        __syncthreads();
        sd[t] += x;
        __syncthreads();
    }
    if (t < nb) bsum[t] = sd[t] - v;   // exclusive
}

__global__ __launch_bounds__(256) void k_scan3(int* __restrict__ row_ptr, const int* __restrict__ bsum,
                                               int n, int E) {
    int i = blockIdx.x * 256 + threadIdx.x;
    if (i < n) row_ptr[i] += bsum[i >> 10];
    if (i == 0) row_ptr[n] = E;
}

// ---------------- GEMM1: h1 = (h @ W1) * rs_out[row]  (M x 256 @ 256 x 128) ----------------
__global__ __launch_bounds__(256) void k_gemm1(const float* __restrict__ A, const float* __restrict__ B,
                                               const float* __restrict__ rs_out, float* __restrict__ C, int M) {
    __shared__ float As[16 * 68];    // [k][row], row dim padded 64->68 (2-way bank alias = free)
    __shared__ float Bs[16 * 128];   // [k][col]
    int t = threadIdx.x;
    int tx = t & 15, ty = t >> 4;
    int block_row = blockIdx.x * 64;
    int a_r = t >> 2;          // 0..63
    int a_k = (t & 3) * 4;     // 0,4,8,12
    float acc[4][8] = {};
    for (int k0 = 0; k0 < IN_DIM; k0 += 16) {
        int gr = block_row + a_r;
        float4 av = {0.f, 0.f, 0.f, 0.f};
        if (gr < M) av = *(const float4*)(A + (size_t)gr * IN_DIM + k0 + a_k);
        As[(a_k + 0) * 68 + a_r] = av.x;
        As[(a_k + 1) * 68 + a_r] = av.y;
        As[(a_k + 2) * 68 + a_r] = av.z;
        As[(a_k + 3) * 68 + a_r] = av.w;
#pragma unroll
        for (int i = 0; i < 2; ++i) {
            int u = t + i * 256;          // 512 float4 units
            int kb = u >> 5;
            int cu = (u & 31) * 4;
            *(float4*)&Bs[kb * 128 + cu] = *(const float4*)(B + (size_t)(k0 + kb) * HID + cu);
        }
        __syncthreads();
#pragma unroll
        for (int k = 0; k < 16; ++k) {
            float4 a  = *(const float4*)&As[k * 68 + ty * 4];
            float4 b0 = *(const float4*)&Bs[k * 128 + tx * 4];
            float4 b1 = *(const float4*)&Bs[k * 128 + tx * 4 + 64];
            float av4[4] = {a.x, a.y, a.z, a.w};
            float bv[8] = {b0.x, b0.y, b0.z, b0.w, b1.x, b1.y, b1.z, b1.w};
#pragma unroll
            for (int i = 0; i < 4; ++i)
#pragma unroll
                for (int j = 0; j < 8; ++j)
                    acc[i][j] = fmaf(av4[i], bv[j], acc[i][j]);
        }
        __syncthreads();
    }
#pragma unroll
    for (int i = 0; i < 4; ++i) {
        int r = block_row + ty * 4 + i;
        if (r >= M) continue;
        float sc = rs_out[r];
        float4 o0 = {acc[i][0] * sc, acc[i][1] * sc, acc[i][2] * sc, acc[i][3] * sc};
        float4 o1 = {acc[i][4] * sc, acc[i][5] * sc, acc[i][6] * sc, acc[i][7] * sc};
        *(float4*)(C + (size_t)r * HID + tx * 4) = o0;
        *(float4*)(C + (size_t)r * HID + tx * 4 + 64) = o1;
    }
}

// ---------------- SpMM1: x1[d] = relu(rs_in[d] * sum_{e in row d} h1[col[e]] + b1) ----------------
__global__ __launch_bounds__(256) void k_spmm1(const float* __restrict__ h1, const int* __restrict__ rp,
                                               const int* __restrict__ col, const float* __restrict__ rs_in,
                                               const float* __restrict__ b1, float* __restrict__ x1, int n) {
    int w = (blockIdx.x * 256 + threadIdx.x) >> 6;
    int lane = threadIdx.x & 63;
    if (w >= n) return;
    int s = rp[w], e = rp[w + 1];
    const float2* hv = (const float2*)h1;
    float ax = 0.f, ay = 0.f;
    int i = s;
    for (; i + 4 <= e; i += 4) {
        int c0 = col[i], c1 = col[i + 1], c2 = col[i + 2], c3 = col[i + 3];
        float2 v0 = hv[(size_t)c0 * 64 + lane];
        float2 v1 = hv[(size_t)c1 * 64 + lane];
        float2 v2 = hv[(size_t)c2 * 64 + lane];
        float2 v3 = hv[(size_t)c3 * 64 + lane];
        ax += (v0.x + v1.x) + (v2.x + v3.x);
        ay += (v0.y + v1.y) + (v2.y + v3.y);
    }
    for (; i < e; ++i) {
        float2 v = hv[(size_t)col[i] * 64 + lane];
        ax += v.x; ay += v.y;
    }
    float sc = rs_in[w];
    float2 bb = ((const float2*)b1)[lane];
    float ox = fmaxf(fmaf(ax, sc, bb.x), 0.f);
    float oy = fmaxf(fmaf(ay, sc, bb.y), 0.f);
    ((float2*)x1)[(size_t)w * 64 + lane] = make_float2(ox, oy);
}

// ---------------- GEMM2: h2 = (x1 @ W2) * rs_out[row]  (M x 128 @ 128 x 40) ----------------
__global__ __launch_bounds__(256) void k_gemm2(const float* __restrict__ A, const float* __restrict__ B,
                                               const float* __restrict__ rs_out, float* __restrict__ C, int M) {
    __shared__ float As[64 * 132];       // [row][k], k-pitch 132
    __shared__ float Wt[OUT_DIM * 132];  // [col][k]
    int t = threadIdx.x;
    int base_row = blockIdx.x * 64;
    for (int i = 0; i < 20; ++i) {
        int flat = t + i * 256;          // 5120
        int k = flat / 40, c = flat - k * 40;
        Wt[c * 132 + k] = B[flat];
    }
#pragma unroll
    for (int i = 0; i < 8; ++i) {
        int u = t + i * 256;
        int row = u >> 5, kc = (u & 31) * 4;
        int gr = base_row + row;
        float4 v = {0.f, 0.f, 0.f, 0.f};
        if (gr < M) v = *(const float4*)(A + (size_t)gr * HID + kc);
        *(float4*)&As[row * 132 + kc] = v;
    }
    __syncthreads();
    int cg = t & 7, rg = t >> 3;
    int c0 = cg * 5, r0 = rg * 2;
    float acc[2][5] = {};
    for (int k = 0; k < HID; k += 4) {
        float4 a0 = *(const float4*)&As[r0 * 132 + k];
        float4 a1 = *(const float4*)&As[(r0 + 1) * 132 + k];
#pragma unroll
        for (int j = 0; j < 5; ++j) {
            float4 wv = *(const float4*)&Wt[(c0 + j) * 132 + k];
            acc[0][j] = fmaf(a0.x, wv.x, acc[0][j]);
            acc[0][j] = fmaf(a0.y, wv.y, acc[0][j]);
            acc[0][j] = fmaf(a0.z, wv.z, acc[0][j]);
            acc[0][j] = fmaf(a0.w, wv.w, acc[0][j]);
            acc[1][j] = fmaf(a1.x, wv.x, acc[1][j]);
            acc[1][j] = fmaf(a1.y, wv.y, acc[1][j]);
            acc[1][j] = fmaf(a1.z, wv.z, acc[1][j]);
            acc[1][j] = fmaf(a1.w, wv.w, acc[1][j]);
        }
    }
#pragma unroll
    for (int ri = 0; ri < 2; ++ri) {
        int r = base_row + r0 + ri;
        if (r < M) {
            float sc = rs_out[r];
#pragma unroll
            for (int j = 0; j < 5; ++j)
                C[(size_t)r * OUT_DIM + c0 + j] = acc[ri][j] * sc;
        }
    }
}

// ---------------- SpMM2 + bias + log_softmax ----------------
__global__ __launch_bounds__(256) void k_spmm2(const float* __restrict__ h2, const int* __restrict__ rp,
                                               const int* __restrict__ col, const float* __restrict__ rs_in,
                                               const float* __restrict__ b2, float* __restrict__ out, int n) {
    int w = (blockIdx.x * 256 + threadIdx.x) >> 6;
    int lane = threadIdx.x & 63;
    if (w >= n) return;
    int f = (lane < OUT_DIM) ? lane : (OUT_DIM - 1);
    int s = rp[w], e = rp[w + 1];
    float acc = 0.f;
    int i = s;
    for (; i + 4 <= e; i += 4) {
        int c0 = col[i], c1 = col[i + 1], c2 = col[i + 2], c3 = col[i + 3];
        float v0 = h2[(size_t)c0 * OUT_DIM + f];
        float v1 = h2[(size_t)c1 * OUT_DIM + f];
        float v2 = h2[(size_t)c2 * OUT_DIM + f];
        float v3 = h2[(size_t)c3 * OUT_DIM + f];
        acc += (v0 + v1) + (v2 + v3);
    }
    for (; i < e; ++i) acc += h2[(size_t)col[i] * OUT_DIM + f];
    float v = fmaf(acc, rs_in[w], b2[f]);
    float vm = (lane < OUT_DIM) ? v : -INFINITY;
    for (int o = 32; o; o >>= 1) vm = fmaxf(vm, __shfl_xor(vm, o, 64));
    float ex = (lane < OUT_DIM) ? expf(v - vm) : 0.f;
    float sum = ex;
    for (int o = 32; o; o >>= 1) sum += __shfl_xor(sum, o, 64);
    if (lane < OUT_DIM) out[(size_t)w * OUT_DIM + lane] = v - vm - logf(sum);
}

// ---------------- launch ----------------

extern "C" void kernel_launch(void* const* d_in, const int* in_sizes, int n_in,
                              void* d_out, int out_size, void* d_ws, size_t ws_size,
                              hipStream_t stream) {
    const int N = in_sizes[0] / IN_DIM;
    const int E = in_sizes[5];
    const float* h  = (const float*)d_in[0];
    const float* W1 = (const float*)d_in[1];
    const float* b1 = (const float*)d_in[2];
    const float* W2 = (const float*)d_in[3];
    const float* b2 = (const float*)d_in[4];
    const int* src  = (const int*)d_in[5];
    const int* dst  = (const int*)d_in[6];
    float* out = (float*)d_out;

    const int NBINS  = (N + BIN_SIZE - 1) >> BIN_SHIFT;   // 98
    const int NCHUNK = (E + CHUNK - 1) / CHUNK;           // 196

    char* w = (char*)d_ws;
    size_t off = 0;
    auto alloc = [&](size_t bytes) -> void* {
        void* p = w + off;
        off += (bytes + 255) & ~(size_t)255;
        return p;
    };
    int* deg_in   = (int*)alloc((size_t)N * 4);
    int* row_ptr  = (int*)alloc((size_t)(N + 1) * 4);
    int* bsum     = (int*)alloc(1024 * 4);
    float* rs_out = (float*)alloc((size_t)N * 4);
    float* rs_in  = (float*)alloc((size_t)N * 4);
    int* col      = (int*)alloc((size_t)E * 4);
    int* bboD     = (int*)alloc((size_t)NCHUNK * (NBINS + 1) * 4);
    int* bboS     = (int*)alloc((size_t)NCHUNK * (NBINS + 1) * 4);
    float* h1     = (float*)alloc((size_t)N * HID * 4);
    float* x1     = (float*)alloc((size_t)N * HID * 4);
    float* h2     = h1;                       // h1 dead after spmm1
    uint32_t* stD = (uint32_t*)x1;            // staging dead before spmm1 writes x1
    unsigned short* stS = (unsigned short*)(x1 + (size_t)E);

    int gN = (N + 255) / 256;
    int NB = (N + 1023) / 1024;

    k_binscatter<<<NCHUNK, 256, 0, stream>>>(src, dst, stD, stS, bboD, bboS, E, NBINS);
    k_deg_src<<<NBINS, 256, 0, stream>>>(stS, bboS, rs_out, N, NCHUNK, NBINS);
    k_deg_dst<<<NBINS, 256, 0, stream>>>(stD, bboD, deg_in, rs_in, N, NCHUNK, NBINS);
    k_scan1<<<NB, 256, 0, stream>>>(deg_in, row_ptr, bsum, N);
    k_scan2<<<1, 1024, 0, stream>>>(bsum, NB);
    k_scan3<<<gN, 256, 0, stream>>>(row_ptr, bsum, N, E);
    k_col<<<NBINS, 256, 0, stream>>>(stD, bboD, row_ptr, col, N, NCHUNK, NBINS);
    k_gemm1<<<(N + 63) / 64, 256, 0, stream>>>(h, W1, rs_out, h1, N);
    k_spmm1<<<(N + 3) / 4, 256, 0, stream>>>(h1, row_ptr, col, rs_in, b1, x1, N);
    k_gemm2<<<(N + 63) / 64, 256, 0, stream>>>(x1, W2, rs_out, h2, N);
    k_spmm2<<<(N + 3) / 4, 256, 0, stream>>>(h2, row_ptr, col, rs_in, b2, out, N);
}

// Round 3
// 807.793 us; speedup vs baseline: 1.3724x; 1.1019x over previous
//
#include <hip/hip_runtime.h>
#include <hip/hip_bf16.h>
#include <cstddef>
#include <cstdint>

#define IN_DIM 256
#define HID 128
#define OUT_DIM 40

#define CHUNK 16384     // edges per binscatter block (private staging region)
#define BIN_SHIFT 10    // 1024 nodes per bin
#define BIN_SIZE 1024
#define MAXB 128        // >= NBINS+1 (NBINS = ceil(100000/1024) = 98)

typedef __attribute__((ext_vector_type(8))) short short8;
typedef __attribute__((ext_vector_type(4))) float f32x4;

__device__ inline short f2bf(float f) {
    __hip_bfloat16 b = __float2bfloat16(f);   // RNE
    return __builtin_bit_cast(short, b);
}
__device__ inline float bf2f(unsigned short u) {
    unsigned int v = (unsigned int)u << 16;
    return __builtin_bit_cast(float, v);
}

// ---------------- CSR build: chunk-private counting sort by dst/src bin ----------------
__global__ __launch_bounds__(256) void k_binscatter(const int* __restrict__ src, const int* __restrict__ dst,
                                                    uint32_t* __restrict__ stD, unsigned short* __restrict__ stS,
                                                    int* __restrict__ bboD, int* __restrict__ bboS,
                                                    int E, int NBINS) {
    __shared__ int hD[MAXB], hS[MAXB], cD[MAXB], cS[MAXB], sd[MAXB];
    int j = blockIdx.x, t = threadIdx.x;
    int base = j * CHUNK;
    int nE = min(CHUNK, E - base);
    int NB1 = NBINS + 1;
    for (int i = t; i < MAXB; i += 256) { hD[i] = 0; hS[i] = 0; }
    __syncthreads();
    for (int i = t; i < nE; i += 256) {
        atomicAdd(&hD[dst[base + i] >> BIN_SHIFT], 1);
        atomicAdd(&hS[src[base + i] >> BIN_SHIFT], 1);
    }
    __syncthreads();
    if (t < MAXB) sd[t] = hD[t];
    __syncthreads();
    for (int off = 1; off < MAXB; off <<= 1) {
        int x = 0;
        if (t < MAXB && t >= off) x = sd[t - off];
        __syncthreads();
        if (t < MAXB) sd[t] += x;
        __syncthreads();
    }
    if (t < MAXB) cD[t] = sd[t] - hD[t];
    if (t < NBINS) bboD[(size_t)j * NB1 + t] = sd[t] - hD[t];
    if (t == NBINS) bboD[(size_t)j * NB1 + NBINS] = nE;
    __syncthreads();
    if (t < MAXB) sd[t] = hS[t];
    __syncthreads();
    for (int off = 1; off < MAXB; off <<= 1) {
        int x = 0;
        if (t < MAXB && t >= off) x = sd[t - off];
        __syncthreads();
        if (t < MAXB) sd[t] += x;
        __syncthreads();
    }
    if (t < MAXB) cS[t] = sd[t] - hS[t];
    if (t < NBINS) bboS[(size_t)j * NB1 + t] = sd[t] - hS[t];
    if (t == NBINS) bboS[(size_t)j * NB1 + NBINS] = nE;
    __syncthreads();
    for (int i = t; i < nE; i += 256) {
        int s = src[base + i], d = dst[base + i];
        int pD = atomicAdd(&cD[d >> BIN_SHIFT], 1);
        stD[(size_t)base + pD] = ((uint32_t)(d & (BIN_SIZE - 1)) << 17) | (uint32_t)s;
        int pS = atomicAdd(&cS[s >> BIN_SHIFT], 1);
        stS[(size_t)base + pS] = (unsigned short)(s & (BIN_SIZE - 1));
    }
}

__global__ __launch_bounds__(256) void k_deg_dst(const uint32_t* __restrict__ stD, const int* __restrict__ bboD,
                                                 int* __restrict__ deg_in, float* __restrict__ rs_in,
                                                 int N, int nchunk, int NBINS) {
    __shared__ int hist[BIN_SIZE];
    int b = blockIdx.x, t = threadIdx.x;
    int NB1 = NBINS + 1;
    for (int i = t; i < BIN_SIZE; i += 256) hist[i] = 0;
    __syncthreads();
    for (int j = 0; j < nchunk; ++j) {
        int s = bboD[(size_t)j * NB1 + b], e = bboD[(size_t)j * NB1 + b + 1];
        const uint32_t* seg = stD + (size_t)j * CHUNK;
        for (int i = s + t; i < e; i += 256)
            atomicAdd(&hist[seg[i] >> 17], 1);
    }
    __syncthreads();
    int base = b << BIN_SHIFT;
    for (int i = t; i < BIN_SIZE; i += 256) {
        int node = base + i;
        if (node < N) {
            int d = hist[i];
            deg_in[node] = d;
            rs_in[node] = rsqrtf((float)max(d, 1));
        }
    }
}

__global__ __launch_bounds__(256) void k_deg_src(const unsigned short* __restrict__ stS, const int* __restrict__ bboS,
                                                 float* __restrict__ rs_out, int N, int nchunk, int NBINS) {
    __shared__ int hist[BIN_SIZE];
    int b = blockIdx.x, t = threadIdx.x;
    int NB1 = NBINS + 1;
    for (int i = t; i < BIN_SIZE; i += 256) hist[i] = 0;
    __syncthreads();
    for (int j = 0; j < nchunk; ++j) {
        int s = bboS[(size_t)j * NB1 + b], e = bboS[(size_t)j * NB1 + b + 1];
        const unsigned short* seg = stS + (size_t)j * CHUNK;
        for (int i = s + t; i < e; i += 256)
            atomicAdd(&hist[seg[i]], 1);
    }
    __syncthreads();
    int base = b << BIN_SHIFT;
    for (int i = t; i < BIN_SIZE; i += 256) {
        int node = base + i;
        if (node < N) rs_out[node] = rsqrtf((float)max(hist[i], 1));
    }
}

__global__ __launch_bounds__(256) void k_col(const uint32_t* __restrict__ stD, const int* __restrict__ bboD,
                                             const int* __restrict__ row_ptr, int* __restrict__ col,
                                             int N, int nchunk, int NBINS) {
    __shared__ int cur[BIN_SIZE];
    int b = blockIdx.x, t = threadIdx.x;
    int NB1 = NBINS + 1;
    int base = b << BIN_SHIFT;
    for (int i = t; i < BIN_SIZE; i += 256) {
        int node = base + i;
        cur[i] = (node < N) ? row_ptr[node] : 0;
    }
    __syncthreads();
    for (int j = 0; j < nchunk; ++j) {
        int s = bboD[(size_t)j * NB1 + b], e = bboD[(size_t)j * NB1 + b + 1];
        const uint32_t* seg = stD + (size_t)j * CHUNK;
        for (int i = s + t; i < e; i += 256) {
            uint32_t v = seg[i];
            int pos = atomicAdd(&cur[v >> 17], 1);
            col[pos] = (int)(v & 0x1FFFFu);
        }
    }
}

__global__ __launch_bounds__(256) void k_scan1(const int* __restrict__ deg, int* __restrict__ out,
                                               int* __restrict__ bsum, int n) {
    __shared__ int sd[256];
    int t = threadIdx.x, b = blockIdx.x;
    int base = b * 1024 + t * 4;
    int v0 = 0, v1 = 0, v2 = 0, v3 = 0;
    if (base + 0 < n) v0 = deg[base + 0];
    if (base + 1 < n) v1 = deg[base + 1];
    if (base + 2 < n) v2 = deg[base + 2];
    if (base + 3 < n) v3 = deg[base + 3];
    int ts = v0 + v1 + v2 + v3;
    sd[t] = ts;
    __syncthreads();
    for (int off = 1; off < 256; off <<= 1) {
        int x = 0;
        if (t >= off) x = sd[t - off];
        __syncthreads();
        sd[t] += x;
        __syncthreads();
    }
    int excl = sd[t] - ts;
    if (base + 0 < n) out[base + 0] = excl;
    if (base + 1 < n) out[base + 1] = excl + v0;
    if (base + 2 < n) out[base + 2] = excl + v0 + v1;
    if (base + 3 < n) out[base + 3] = excl + v0 + v1 + v2;
    if (t == 255) bsum[b] = sd[255];
}

__global__ __launch_bounds__(1024) void k_scan2(int* __restrict__ bsum, int nb) {
    __shared__ int sd[1024];
    int t = threadIdx.x;
    int v = (t < nb) ? bsum[t] : 0;
    sd[t] = v;
    __syncthreads();
    for (int off = 1; off < 1024; off <<= 1) {
        int x = 0;
        if (t >= off) x = sd[t - off];
        __syncthreads();
        sd[t] += x;
        __syncthreads();
    }
    if (t < nb) bsum[t] = sd[t] - v;   // exclusive
}

__global__ __launch_bounds__(256) void k_scan3(int* __restrict__ row_ptr, const int* __restrict__ bsum,
                                               int n, int E) {
    int i = blockIdx.x * 256 + threadIdx.x;
    if (i < n) row_ptr[i] += bsum[i >> 10];
    if (i == 0) row_ptr[n] = E;
}

// ---------------- GEMM1 (bf16 MFMA): h1 = bf16((h @ W1) * rs_out[row]) ----------------
// Block: 256 thr = 4 waves. Tile M=64 (wave w: rows w*16..+15), N=128 (8 tiles of 16), K step 32.
// W1 pre-staged to LDS in MFMA-fragment order: Wfrag[nt][ks][lane][8] -> conflict-free b128.
// Layouts (verified gfx950 16x16x32): A[m=lane&15][k=quad*8+j]; B[n=lane&15][k=quad*8+j];
// D: col=lane&15, row=quad*4+reg.
__global__ __launch_bounds__(256) void k_gemm1(const float* __restrict__ A, const float* __restrict__ B,
                                               const float* __restrict__ rs_out, short* __restrict__ C, int M) {
    __shared__ short Wfrag[8 * 8 * 64 * 8];   // 64 KB
    __shared__ short As[64 * 40];             // 64 rows x 32 k, pitch 40 (5 KB)
    int t = threadIdx.x;
    int lane = t & 63, wv = t >> 6;
    int block_row = blockIdx.x * 64;

    // stage W1 (256x128 fp32) -> Wfrag, coalesced float4 global reads
#pragma unroll
    for (int i = 0; i < 32; ++i) {
        int u = t + i * 256;                  // 8192 float4 units
        int k = u >> 5;                       // 0..255
        int n0 = (u & 31) * 4;
        float4 v = *(const float4*)(B + (size_t)k * HID + n0);
        int ks = k >> 5, quad = (k >> 3) & 3, j = k & 7;
        float vv[4] = {v.x, v.y, v.z, v.w};
#pragma unroll
        for (int e = 0; e < 4; ++e) {
            int n = n0 + e;
            int nt = n >> 4;
            int ln = (n & 15) | (quad << 4);
            Wfrag[(((nt * 8 + ks) * 64) + ln) * 8 + j] = f2bf(vv[e]);
        }
    }

    f32x4 acc[8] = {};
#pragma unroll
    for (int ks = 0; ks < 8; ++ks) {
        int k0 = ks * 32;
        // stage A tile 64x32 fp32 -> bf16
#pragma unroll
        for (int i = 0; i < 2; ++i) {
            int u = t + i * 256;              // 512 float4 units
            int row = u >> 3, kq = (u & 7) * 4;
            int gr = block_row + row;
            float4 v = {0.f, 0.f, 0.f, 0.f};
            if (gr < M) v = *(const float4*)(A + (size_t)gr * IN_DIM + k0 + kq);
            short4 sv = {f2bf(v.x), f2bf(v.y), f2bf(v.z), f2bf(v.w)};
            *(short4*)&As[row * 40 + kq] = sv;
        }
        __syncthreads();
        short8 a = *(short8*)&As[(wv * 16 + (lane & 15)) * 40 + (lane >> 4) * 8];
#pragma unroll
        for (int nt = 0; nt < 8; ++nt) {
            short8 b = *(short8*)&Wfrag[(((nt * 8 + ks) * 64) + lane) * 8];
            acc[nt] = __builtin_amdgcn_mfma_f32_16x16x32_bf16(a, b, acc[nt], 0, 0, 0);
        }
        __syncthreads();
    }

    // epilogue: scale by rs_out, store bf16
    int quad = lane >> 4;
    float sc[4];
    int rows[4];
#pragma unroll
    for (int r = 0; r < 4; ++r) {
        rows[r] = block_row + wv * 16 + quad * 4 + r;
        sc[r] = (rows[r] < M) ? rs_out[rows[r]] : 0.f;
    }
#pragma unroll
    for (int nt = 0; nt < 8; ++nt) {
        int c = nt * 16 + (lane & 15);
#pragma unroll
        for (int r = 0; r < 4; ++r) {
            if (rows[r] < M)
                C[(size_t)rows[r] * HID + c] = f2bf(acc[nt][r] * sc[r]);
        }
    }
}

// ---------------- SpMM1: x1[d] = relu(rs_in[d] * sum h1_bf16[col[e]] + b1) ----------------
// one wave per dst node; lane holds 2 bf16 feats packed in one u32 (256 B/row, fully coalesced)
__global__ __launch_bounds__(256) void k_spmm1(const uint32_t* __restrict__ h1, const int* __restrict__ rp,
                                               const int* __restrict__ col, const float* __restrict__ rs_in,
                                               const float* __restrict__ b1, float* __restrict__ x1, int n) {
    int w = (blockIdx.x * 256 + threadIdx.x) >> 6;
    int lane = threadIdx.x & 63;
    if (w >= n) return;
    int s = rp[w], e = rp[w + 1];
    float ax = 0.f, ay = 0.f;
    int i = s;
    for (; i + 4 <= e; i += 4) {
        int c0 = col[i], c1 = col[i + 1], c2 = col[i + 2], c3 = col[i + 3];
        uint32_t u0 = h1[(size_t)c0 * 64 + lane];
        uint32_t u1 = h1[(size_t)c1 * 64 + lane];
        uint32_t u2 = h1[(size_t)c2 * 64 + lane];
        uint32_t u3 = h1[(size_t)c3 * 64 + lane];
        ax += (bf2f((unsigned short)u0) + bf2f((unsigned short)u1)) +
              (bf2f((unsigned short)u2) + bf2f((unsigned short)u3));
        ay += (bf2f((unsigned short)(u0 >> 16)) + bf2f((unsigned short)(u1 >> 16))) +
              (bf2f((unsigned short)(u2 >> 16)) + bf2f((unsigned short)(u3 >> 16)));
    }
    for (; i < e; ++i) {
        uint32_t u = h1[(size_t)col[i] * 64 + lane];
        ax += bf2f((unsigned short)u);
        ay += bf2f((unsigned short)(u >> 16));
    }
    float sc = rs_in[w];
    float2 bb = ((const float2*)b1)[lane];
    float ox = fmaxf(fmaf(ax, sc, bb.x), 0.f);
    float oy = fmaxf(fmaf(ay, sc, bb.y), 0.f);
    ((float2*)x1)[(size_t)w * 64 + lane] = make_float2(ox, oy);
}

// ---------------- GEMM2: h2_bf16 = (x1 @ W2) * rs_out[row]  (M x 128 @ 128 x 40) ----------------
__global__ __launch_bounds__(256) void k_gemm2(const float* __restrict__ A, const float* __restrict__ B,
                                               const float* __restrict__ rs_out, short* __restrict__ C, int M) {
    __shared__ float As[64 * 132];       // [row][k], k-pitch 132
    __shared__ float Wt[OUT_DIM * 132];  // [col][k]
    int t = threadIdx.x;
    int base_row = blockIdx.x * 64;
    for (int i = 0; i < 20; ++i) {
        int flat = t + i * 256;          // 5120
        int k = flat / 40, c = flat - k * 40;
        Wt[c * 132 + k] = B[flat];
    }
#pragma unroll
    for (int i = 0; i < 8; ++i) {
        int u = t + i * 256;
        int row = u >> 5, kc = (u & 31) * 4;
        int gr = base_row + row;
        float4 v = {0.f, 0.f, 0.f, 0.f};
        if (gr < M) v = *(const float4*)(A + (size_t)gr * HID + kc);
        *(float4*)&As[row * 132 + kc] = v;
    }
    __syncthreads();
    int cg = t & 7, rg = t >> 3;
    int c0 = cg * 5, r0 = rg * 2;
    float acc[2][5] = {};
    for (int k = 0; k < HID; k += 4) {
        float4 a0 = *(const float4*)&As[r0 * 132 + k];
        float4 a1 = *(const float4*)&As[(r0 + 1) * 132 + k];
#pragma unroll
        for (int j = 0; j < 5; ++j) {
            float4 wv = *(const float4*)&Wt[(c0 + j) * 132 + k];
            acc[0][j] = fmaf(a0.x, wv.x, acc[0][j]);
            acc[0][j] = fmaf(a0.y, wv.y, acc[0][j]);
            acc[0][j] = fmaf(a0.z, wv.z, acc[0][j]);
            acc[0][j] = fmaf(a0.w, wv.w, acc[0][j]);
            acc[1][j] = fmaf(a1.x, wv.x, acc[1][j]);
            acc[1][j] = fmaf(a1.y, wv.y, acc[1][j]);
            acc[1][j] = fmaf(a1.z, wv.z, acc[1][j]);
            acc[1][j] = fmaf(a1.w, wv.w, acc[1][j]);
        }
    }
#pragma unroll
    for (int ri = 0; ri < 2; ++ri) {
        int r = base_row + r0 + ri;
        if (r < M) {
            float sc = rs_out[r];
#pragma unroll
            for (int j = 0; j < 5; ++j)
                C[(size_t)r * OUT_DIM + c0 + j] = f2bf(acc[ri][j] * sc);
        }
    }
}

// ---------------- SpMM2 + bias + log_softmax (h2 is bf16) ----------------
__global__ __launch_bounds__(256) void k_spmm2(const unsigned short* __restrict__ h2, const int* __restrict__ rp,
                                               const int* __restrict__ col, const float* __restrict__ rs_in,
                                               const float* __restrict__ b2, float* __restrict__ out, int n) {
    int w = (blockIdx.x * 256 + threadIdx.x) >> 6;
    int lane = threadIdx.x & 63;
    if (w >= n) return;
    int f = (lane < OUT_DIM) ? lane : (OUT_DIM - 1);
    int s = rp[w], e = rp[w + 1];
    float acc = 0.f;
    int i = s;
    for (; i + 4 <= e; i += 4) {
        int c0 = col[i], c1 = col[i + 1], c2 = col[i + 2], c3 = col[i + 3];
        float v0 = bf2f(h2[(size_t)c0 * OUT_DIM + f]);
        float v1 = bf2f(h2[(size_t)c1 * OUT_DIM + f]);
        float v2 = bf2f(h2[(size_t)c2 * OUT_DIM + f]);
        float v3 = bf2f(h2[(size_t)c3 * OUT_DIM + f]);
        acc += (v0 + v1) + (v2 + v3);
    }
    for (; i < e; ++i) acc += bf2f(h2[(size_t)col[i] * OUT_DIM + f]);
    float v = fmaf(acc, rs_in[w], b2[f]);
    float vm = (lane < OUT_DIM) ? v : -INFINITY;
    for (int o = 32; o; o >>= 1) vm = fmaxf(vm, __shfl_xor(vm, o, 64));
    float ex = (lane < OUT_DIM) ? expf(v - vm) : 0.f;
    float sum = ex;
    for (int o = 32; o; o >>= 1) sum += __shfl_xor(sum, o, 64);
    if (lane < OUT_DIM) out[(size_t)w * OUT_DIM + lane] = v - vm - logf(sum);
}

// ---------------- launch ----------------

extern "C" void kernel_launch(void* const* d_in, const int* in_sizes, int n_in,
                              void* d_out, int out_size, void* d_ws, size_t ws_size,
                              hipStream_t stream) {
    const int N = in_sizes[0] / IN_DIM;
    const int E = in_sizes[5];
    const float* h  = (const float*)d_in[0];
    const float* W1 = (const float*)d_in[1];
    const float* b1 = (const float*)d_in[2];
    const float* W2 = (const float*)d_in[3];
    const float* b2 = (const float*)d_in[4];
    const int* src  = (const int*)d_in[5];
    const int* dst  = (const int*)d_in[6];
    float* out = (float*)d_out;

    const int NBINS  = (N + BIN_SIZE - 1) >> BIN_SHIFT;   // 98
    const int NCHUNK = (E + CHUNK - 1) / CHUNK;           // 196

    char* w = (char*)d_ws;
    size_t off = 0;
    auto alloc = [&](size_t bytes) -> void* {
        void* p = w + off;
        off += (bytes + 255) & ~(size_t)255;
        return p;
    };
    int* deg_in   = (int*)alloc((size_t)N * 4);
    int* row_ptr  = (int*)alloc((size_t)(N + 1) * 4);
    int* bsum     = (int*)alloc(1024 * 4);
    float* rs_out = (float*)alloc((size_t)N * 4);
    float* rs_in  = (float*)alloc((size_t)N * 4);
    int* col      = (int*)alloc((size_t)E * 4);
    int* bboD     = (int*)alloc((size_t)NCHUNK * (NBINS + 1) * 4);
    int* bboS     = (int*)alloc((size_t)NCHUNK * (NBINS + 1) * 4);
    short* h1     = (short*)alloc((size_t)N * HID * 2);   // bf16
    float* x1     = (float*)alloc((size_t)N * HID * 4);   // fp32
    short* h2     = h1;                       // h1 dead after spmm1; 8 MB <= 25.6 MB
    uint32_t* stD = (uint32_t*)x1;            // staging dead before spmm1 writes x1
    unsigned short* stS = (unsigned short*)(x1 + (size_t)E);

    int gN = (N + 255) / 256;
    int NB = (N + 1023) / 1024;

    k_binscatter<<<NCHUNK, 256, 0, stream>>>(src, dst, stD, stS, bboD, bboS, E, NBINS);
    k_deg_src<<<NBINS, 256, 0, stream>>>(stS, bboS, rs_out, N, NCHUNK, NBINS);
    k_deg_dst<<<NBINS, 256, 0, stream>>>(stD, bboD, deg_in, rs_in, N, NCHUNK, NBINS);
    k_scan1<<<NB, 256, 0, stream>>>(deg_in, row_ptr, bsum, N);
    k_scan2<<<1, 1024, 0, stream>>>(bsum, NB);
    k_scan3<<<gN, 256, 0, stream>>>(row_ptr, bsum, N, E);
    k_col<<<NBINS, 256, 0, stream>>>(stD, bboD, row_ptr, col, N, NCHUNK, NBINS);
    k_gemm1<<<(N + 63) / 64, 256, 0, stream>>>(h, W1, rs_out, h1, N);
    k_spmm1<<<(N + 3) / 4, 256, 0, stream>>>((const uint32_t*)h1, row_ptr, col, rs_in, b1, x1, N);
    k_gemm2<<<(N + 63) / 64, 256, 0, stream>>>(x1, W2, rs_out, h2, N);
    k_spmm2<<<(N + 3) / 4, 256, 0, stream>>>((const unsigned short*)h2, row_ptr, col, rs_in, b2, out, N);
}

// Round 4
// 620.956 us; speedup vs baseline: 1.7853x; 1.3009x over previous
//
#include <hip/hip_runtime.h>
#include <hip/hip_bf16.h>
#include <cstddef>
#include <cstdint>

#define IN_DIM 256
#define HID 128
#define OUT_DIM 40

#define CHUNK 8192      // edges per binscatter block (private staging region)
#define BIN_SHIFT 10    // 1024 nodes per bin
#define BIN_SIZE 1024
#define MAXB 128        // >= NBINS+1 (NBINS = ceil(100000/1024) = 98)
#define GSPLIT 8        // blocks per bin for deg/col kernels

typedef __attribute__((ext_vector_type(8))) short short8;
typedef __attribute__((ext_vector_type(4))) float f32x4;

__device__ inline short f2bf(float f) {
    __hip_bfloat16 b = __float2bfloat16(f);   // RNE
    return __builtin_bit_cast(short, b);
}
__device__ inline float bf2f(unsigned short u) {
    unsigned int v = (unsigned int)u << 16;
    return __builtin_bit_cast(float, v);
}

// ---------------- CSR build: chunk-private counting sort by dst/src bin ----------------
__global__ __launch_bounds__(256) void k_binscatter(const int* __restrict__ src, const int* __restrict__ dst,
                                                    uint32_t* __restrict__ stD, unsigned short* __restrict__ stS,
                                                    int* __restrict__ bboD, int* __restrict__ bboS,
                                                    int E, int NBINS) {
    __shared__ int hD[MAXB], hS[MAXB], cD[MAXB], cS[MAXB], sd[MAXB];
    int j = blockIdx.x, t = threadIdx.x;
    int base = j * CHUNK;
    int nE = min(CHUNK, E - base);
    int NB1 = NBINS + 1;
    for (int i = t; i < MAXB; i += 256) { hD[i] = 0; hS[i] = 0; }
    __syncthreads();
    for (int i = t; i < nE; i += 256) {
        atomicAdd(&hD[dst[base + i] >> BIN_SHIFT], 1);
        atomicAdd(&hS[src[base + i] >> BIN_SHIFT], 1);
    }
    __syncthreads();
    if (t < MAXB) sd[t] = hD[t];
    __syncthreads();
    for (int off = 1; off < MAXB; off <<= 1) {
        int x = 0;
        if (t < MAXB && t >= off) x = sd[t - off];
        __syncthreads();
        if (t < MAXB) sd[t] += x;
        __syncthreads();
    }
    if (t < MAXB) cD[t] = sd[t] - hD[t];
    if (t < NBINS) bboD[(size_t)j * NB1 + t] = sd[t] - hD[t];
    if (t == NBINS) bboD[(size_t)j * NB1 + NBINS] = nE;
    __syncthreads();
    if (t < MAXB) sd[t] = hS[t];
    __syncthreads();
    for (int off = 1; off < MAXB; off <<= 1) {
        int x = 0;
        if (t < MAXB && t >= off) x = sd[t - off];
        __syncthreads();
        if (t < MAXB) sd[t] += x;
        __syncthreads();
    }
    if (t < MAXB) cS[t] = sd[t] - hS[t];
    if (t < NBINS) bboS[(size_t)j * NB1 + t] = sd[t] - hS[t];
    if (t == NBINS) bboS[(size_t)j * NB1 + NBINS] = nE;
    __syncthreads();
    for (int i = t; i < nE; i += 256) {
        int s = src[base + i], d = dst[base + i];
        int pD = atomicAdd(&cD[d >> BIN_SHIFT], 1);
        stD[(size_t)base + pD] = ((uint32_t)(d & (BIN_SIZE - 1)) << 17) | (uint32_t)s;
        int pS = atomicAdd(&cS[s >> BIN_SHIFT], 1);
        stS[(size_t)base + pS] = (unsigned short)(s & (BIN_SIZE - 1));
    }
}

// grid (NBINS, GSPLIT); wave-per-chunk; LDS hist -> one global atomic per nonzero node
__global__ __launch_bounds__(256) void k_deg_dst(const uint32_t* __restrict__ stD, const int* __restrict__ bboD,
                                                 int* __restrict__ deg_in, int N, int nchunk, int NBINS) {
    __shared__ int hist[BIN_SIZE];
    int b = blockIdx.x, g = blockIdx.y, t = threadIdx.x;
    int wv = t >> 6, lane = t & 63;
    int NB1 = NBINS + 1;
    for (int i = t; i < BIN_SIZE; i += 256) hist[i] = 0;
    __syncthreads();
    for (int j = g * 4 + wv; j < nchunk; j += GSPLIT * 4) {
        int s = bboD[(size_t)j * NB1 + b], e = bboD[(size_t)j * NB1 + b + 1];
        const uint32_t* seg = stD + (size_t)j * CHUNK;
        for (int i = s + lane; i < e; i += 64)
            atomicAdd(&hist[seg[i] >> 17], 1);
    }
    __syncthreads();
    int base = b << BIN_SHIFT;
    for (int i = t; i < BIN_SIZE; i += 256) {
        int v = hist[i];
        if (v) atomicAdd(&deg_in[base + i], v);   // node<N guaranteed when v>0
    }
}

__global__ __launch_bounds__(256) void k_deg_src(const unsigned short* __restrict__ stS, const int* __restrict__ bboS,
                                                 int* __restrict__ deg_out, int N, int nchunk, int NBINS) {
    __shared__ int hist[BIN_SIZE];
    int b = blockIdx.x, g = blockIdx.y, t = threadIdx.x;
    int wv = t >> 6, lane = t & 63;
    int NB1 = NBINS + 1;
    for (int i = t; i < BIN_SIZE; i += 256) hist[i] = 0;
    __syncthreads();
    for (int j = g * 4 + wv; j < nchunk; j += GSPLIT * 4) {
        int s = bboS[(size_t)j * NB1 + b], e = bboS[(size_t)j * NB1 + b + 1];
        const unsigned short* seg = stS + (size_t)j * CHUNK;
        for (int i = s + lane; i < e; i += 64)
            atomicAdd(&hist[seg[i]], 1);
    }
    __syncthreads();
    int base = b << BIN_SHIFT;
    for (int i = t; i < BIN_SIZE; i += 256) {
        int v = hist[i];
        if (v) atomicAdd(&deg_out[base + i], v);
    }
}

// grid (NBINS, GSPLIT): pass1 count, reserve ranges via global cursor, pass2 scatter
__global__ __launch_bounds__(256) void k_col(const uint32_t* __restrict__ stD, const int* __restrict__ bboD,
                                             int* __restrict__ cursor, int* __restrict__ col,
                                             int N, int nchunk, int NBINS) {
    __shared__ int hist[BIN_SIZE];
    int b = blockIdx.x, g = blockIdx.y, t = threadIdx.x;
    int wv = t >> 6, lane = t & 63;
    int NB1 = NBINS + 1;
    for (int i = t; i < BIN_SIZE; i += 256) hist[i] = 0;
    __syncthreads();
    for (int j = g * 4 + wv; j < nchunk; j += GSPLIT * 4) {
        int s = bboD[(size_t)j * NB1 + b], e = bboD[(size_t)j * NB1 + b + 1];
        const uint32_t* seg = stD + (size_t)j * CHUNK;
        for (int i = s + lane; i < e; i += 64)
            atomicAdd(&hist[seg[i] >> 17], 1);
    }
    __syncthreads();
    int base = b << BIN_SHIFT;
    for (int i = t; i < BIN_SIZE; i += 256) {
        int v = hist[i];
        hist[i] = v ? atomicAdd(&cursor[base + i], v) : 0;
    }
    __syncthreads();
    for (int j = g * 4 + wv; j < nchunk; j += GSPLIT * 4) {
        int s = bboD[(size_t)j * NB1 + b], e = bboD[(size_t)j * NB1 + b + 1];
        const uint32_t* seg = stD + (size_t)j * CHUNK;
        for (int i = s + lane; i < e; i += 64) {
            uint32_t v = seg[i];
            int pos = atomicAdd(&hist[v >> 17], 1);
            col[pos] = (int)(v & 0x1FFFFu);
        }
    }
}

// exclusive scan of deg_in -> row_ptr; fused rs_in
__global__ __launch_bounds__(256) void k_scan1(const int* __restrict__ deg, int* __restrict__ out,
                                               int* __restrict__ bsum, float* __restrict__ rs_in, int n) {
    __shared__ int sd[256];
    int t = threadIdx.x, b = blockIdx.x;
    int base = b * 1024 + t * 4;
    int v0 = 0, v1 = 0, v2 = 0, v3 = 0;
    if (base + 0 < n) v0 = deg[base + 0];
    if (base + 1 < n) v1 = deg[base + 1];
    if (base + 2 < n) v2 = deg[base + 2];
    if (base + 3 < n) v3 = deg[base + 3];
    if (base + 0 < n) rs_in[base + 0] = rsqrtf((float)max(v0, 1));
    if (base + 1 < n) rs_in[base + 1] = rsqrtf((float)max(v1, 1));
    if (base + 2 < n) rs_in[base + 2] = rsqrtf((float)max(v2, 1));
    if (base + 3 < n) rs_in[base + 3] = rsqrtf((float)max(v3, 1));
    int ts = v0 + v1 + v2 + v3;
    sd[t] = ts;
    __syncthreads();
    for (int off = 1; off < 256; off <<= 1) {
        int x = 0;
        if (t >= off) x = sd[t - off];
        __syncthreads();
        sd[t] += x;
        __syncthreads();
    }
    int excl = sd[t] - ts;
    if (base + 0 < n) out[base + 0] = excl;
    if (base + 1 < n) out[base + 1] = excl + v0;
    if (base + 2 < n) out[base + 2] = excl + v0 + v1;
    if (base + 3 < n) out[base + 3] = excl + v0 + v1 + v2;
    if (t == 255) bsum[b] = sd[255];
}

__global__ __launch_bounds__(1024) void k_scan2(int* __restrict__ bsum, int nb) {
    __shared__ int sd[1024];
    int t = threadIdx.x;
    int v = (t < nb) ? bsum[t] : 0;
    sd[t] = v;
    __syncthreads();
    for (int off = 1; off < 1024; off <<= 1) {
        int x = 0;
        if (t >= off) x = sd[t - off];
        __syncthreads();
        sd[t] += x;
        __syncthreads();
    }
    if (t < nb) bsum[t] = sd[t] - v;   // exclusive
}

// finalize row_ptr; fused cursor init + rs_out
__global__ __launch_bounds__(256) void k_scan3(int* __restrict__ row_ptr, const int* __restrict__ bsum,
                                               int* __restrict__ cursor, const int* __restrict__ deg_out,
                                               float* __restrict__ rs_out, int n, int E) {
    int i = blockIdx.x * 256 + threadIdx.x;
    if (i < n) {
        int v = row_ptr[i] + bsum[i >> 10];
        row_ptr[i] = v;
        cursor[i] = v;
        rs_out[i] = rsqrtf((float)max(deg_out[i], 1));
    }
    if (i == 0) row_ptr[n] = E;
}

// ---------------- W1 repack (once): fp32 [256][128] -> bf16 fragments [nt][ks][lane][8] ----------------
__global__ __launch_bounds__(256) void k_wrepack(const float* __restrict__ B, short* __restrict__ Wg) {
    int u = blockIdx.x * 256 + threadIdx.x;   // 8192 float4 units
    int k = u >> 5;                           // 0..255
    int n0 = (u & 31) * 4;
    float4 v = *(const float4*)(B + (size_t)k * HID + n0);
    int ks = k >> 5, quad = (k >> 3) & 3, j = k & 7;
    float vv[4] = {v.x, v.y, v.z, v.w};
#pragma unroll
    for (int e = 0; e < 4; ++e) {
        int n = n0 + e;
        int nt = n >> 4;
        int ln = (n & 15) | (quad << 4);
        Wg[(((nt * 8 + ks) * 64) + ln) * 8 + j] = f2bf(vv[e]);
    }
}

// ---------------- GEMM1 (bf16 MFMA): h1 = bf16((h @ W1) * rs_out[row]) ----------------
// A tile 64x256 staged to LDS bf16 once (1 barrier); B fragments read from global Wg (L2-hot).
__global__ __launch_bounds__(256) void k_gemm1(const float* __restrict__ A, const short* __restrict__ Wg,
                                               const float* __restrict__ rs_out, short* __restrict__ C, int M) {
    __shared__ short As[64 * 264];            // [row][k], k-pitch 264 (33 KB)
    int t = threadIdx.x;
    int lane = t & 63, wv = t >> 6;
    int block_row = blockIdx.x * 64;
#pragma unroll
    for (int i = 0; i < 16; ++i) {
        int u = t + i * 256;                  // 4096 float4 units
        int row = u >> 6, kq = (u & 63) * 4;
        int gr = block_row + row;
        float4 v = {0.f, 0.f, 0.f, 0.f};
        if (gr < M) v = *(const float4*)(A + (size_t)gr * IN_DIM + kq);
        short4 sv = {f2bf(v.x), f2bf(v.y), f2bf(v.z), f2bf(v.w)};
        *(short4*)&As[row * 264 + kq] = sv;
    }
    __syncthreads();
    f32x4 acc[8] = {};
    int arow = (wv * 16 + (lane & 15)) * 264 + (lane >> 4) * 8;
#pragma unroll
    for (int ks = 0; ks < 8; ++ks) {
        short8 a = *(short8*)&As[arow + ks * 32];
#pragma unroll
        for (int nt = 0; nt < 8; ++nt) {
            short8 b = *(const short8*)&Wg[(((nt * 8 + ks) * 64) + lane) * 8];
            acc[nt] = __builtin_amdgcn_mfma_f32_16x16x32_bf16(a, b, acc[nt], 0, 0, 0);
        }
    }
    int quad = lane >> 4;
    float sc[4];
    int rows[4];
#pragma unroll
    for (int r = 0; r < 4; ++r) {
        rows[r] = block_row + wv * 16 + quad * 4 + r;
        sc[r] = (rows[r] < M) ? rs_out[rows[r]] : 0.f;
    }
#pragma unroll
    for (int nt = 0; nt < 8; ++nt) {
        int c = nt * 16 + (lane & 15);
#pragma unroll
        for (int r = 0; r < 4; ++r) {
            if (rows[r] < M)
                C[(size_t)rows[r] * HID + c] = f2bf(acc[nt][r] * sc[r]);
        }
    }
}

// ---------------- SpMM1: x1[d] = relu(rs_in[d] * sum h1_bf16[col[e]] + b1) ----------------
__global__ __launch_bounds__(256) void k_spmm1(const uint32_t* __restrict__ h1, const int* __restrict__ rp,
                                               const int* __restrict__ col, const float* __restrict__ rs_in,
                                               const float* __restrict__ b1, float* __restrict__ x1, int n) {
    int w = (blockIdx.x * 256 + threadIdx.x) >> 6;
    int lane = threadIdx.x & 63;
    if (w >= n) return;
    int s = rp[w], e = rp[w + 1];
    float ax = 0.f, ay = 0.f;
    int i = s;
    for (; i + 4 <= e; i += 4) {
        int c0 = col[i], c1 = col[i + 1], c2 = col[i + 2], c3 = col[i + 3];
        uint32_t u0 = h1[(size_t)c0 * 64 + lane];
        uint32_t u1 = h1[(size_t)c1 * 64 + lane];
        uint32_t u2 = h1[(size_t)c2 * 64 + lane];
        uint32_t u3 = h1[(size_t)c3 * 64 + lane];
        ax += (bf2f((unsigned short)u0) + bf2f((unsigned short)u1)) +
              (bf2f((unsigned short)u2) + bf2f((unsigned short)u3));
        ay += (bf2f((unsigned short)(u0 >> 16)) + bf2f((unsigned short)(u1 >> 16))) +
              (bf2f((unsigned short)(u2 >> 16)) + bf2f((unsigned short)(u3 >> 16)));
    }
    for (; i < e; ++i) {
        uint32_t u = h1[(size_t)col[i] * 64 + lane];
        ax += bf2f((unsigned short)u);
        ay += bf2f((unsigned short)(u >> 16));
    }
    float sc = rs_in[w];
    float2 bb = ((const float2*)b1)[lane];
    float ox = fmaxf(fmaf(ax, sc, bb.x), 0.f);
    float oy = fmaxf(fmaf(ay, sc, bb.y), 0.f);
    ((float2*)x1)[(size_t)w * 64 + lane] = make_float2(ox, oy);
}

// ---------------- GEMM2: h2_bf16 = (x1 @ W2) * rs_out[row]  (M x 128 @ 128 x 40) ----------------
__global__ __launch_bounds__(256) void k_gemm2(const float* __restrict__ A, const float* __restrict__ B,
                                               const float* __restrict__ rs_out, short* __restrict__ C, int M) {
    __shared__ float As[64 * 132];       // [row][k], k-pitch 132
    __shared__ float Wt[OUT_DIM * 132];  // [col][k]
    int t = threadIdx.x;
    int base_row = blockIdx.x * 64;
    for (int i = 0; i < 20; ++i) {
        int flat = t + i * 256;          // 5120
        int k = flat / 40, c = flat - k * 40;
        Wt[c * 132 + k] = B[flat];
    }
#pragma unroll
    for (int i = 0; i < 8; ++i) {
        int u = t + i * 256;
        int row = u >> 5, kc = (u & 31) * 4;
        int gr = base_row + row;
        float4 v = {0.f, 0.f, 0.f, 0.f};
        if (gr < M) v = *(const float4*)(A + (size_t)gr * HID + kc);
        *(float4*)&As[row * 132 + kc] = v;
    }
    __syncthreads();
    int cg = t & 7, rg = t >> 3;
    int c0 = cg * 5, r0 = rg * 2;
    float acc[2][5] = {};
    for (int k = 0; k < HID; k += 4) {
        float4 a0 = *(const float4*)&As[r0 * 132 + k];
        float4 a1 = *(const float4*)&As[(r0 + 1) * 132 + k];
#pragma unroll
        for (int j = 0; j < 5; ++j) {
            float4 wv = *(const float4*)&Wt[(c0 + j) * 132 + k];
            acc[0][j] = fmaf(a0.x, wv.x, acc[0][j]);
            acc[0][j] = fmaf(a0.y, wv.y, acc[0][j]);
            acc[0][j] = fmaf(a0.z, wv.z, acc[0][j]);
            acc[0][j] = fmaf(a0.w, wv.w, acc[0][j]);
            acc[1][j] = fmaf(a1.x, wv.x, acc[1][j]);
            acc[1][j] = fmaf(a1.y, wv.y, acc[1][j]);
            acc[1][j] = fmaf(a1.z, wv.z, acc[1][j]);
            acc[1][j] = fmaf(a1.w, wv.w, acc[1][j]);
        }
    }
#pragma unroll
    for (int ri = 0; ri < 2; ++ri) {
        int r = base_row + r0 + ri;
        if (r < M) {
            float sc = rs_out[r];
#pragma unroll
            for (int j = 0; j < 5; ++j)
                C[(size_t)r * OUT_DIM + c0 + j] = f2bf(acc[ri][j] * sc);
        }
    }
}

// ---------------- SpMM2 + bias + log_softmax (h2 is bf16) ----------------
__global__ __launch_bounds__(256) void k_spmm2(const unsigned short* __restrict__ h2, const int* __restrict__ rp,
                                               const int* __restrict__ col, const float* __restrict__ rs_in,
                                               const float* __restrict__ b2, float* __restrict__ out, int n) {
    int w = (blockIdx.x * 256 + threadIdx.x) >> 6;
    int lane = threadIdx.x & 63;
    if (w >= n) return;
    int f = (lane < OUT_DIM) ? lane : (OUT_DIM - 1);
    int s = rp[w], e = rp[w + 1];
    float acc = 0.f;
    int i = s;
    for (; i + 4 <= e; i += 4) {
        int c0 = col[i], c1 = col[i + 1], c2 = col[i + 2], c3 = col[i + 3];
        float v0 = bf2f(h2[(size_t)c0 * OUT_DIM + f]);
        float v1 = bf2f(h2[(size_t)c1 * OUT_DIM + f]);
        float v2 = bf2f(h2[(size_t)c2 * OUT_DIM + f]);
        float v3 = bf2f(h2[(size_t)c3 * OUT_DIM + f]);
        acc += (v0 + v1) + (v2 + v3);
    }
    for (; i < e; ++i) acc += bf2f(h2[(size_t)col[i] * OUT_DIM + f]);
    float v = fmaf(acc, rs_in[w], b2[f]);
    float vm = (lane < OUT_DIM) ? v : -INFINITY;
    for (int o = 32; o; o >>= 1) vm = fmaxf(vm, __shfl_xor(vm, o, 64));
    float ex = (lane < OUT_DIM) ? expf(v - vm) : 0.f;
    float sum = ex;
    for (int o = 32; o; o >>= 1) sum += __shfl_xor(sum, o, 64);
    if (lane < OUT_DIM) out[(size_t)w * OUT_DIM + lane] = v - vm - logf(sum);
}

// ---------------- launch ----------------

extern "C" void kernel_launch(void* const* d_in, const int* in_sizes, int n_in,
                              void* d_out, int out_size, void* d_ws, size_t ws_size,
                              hipStream_t stream) {
    const int N = in_sizes[0] / IN_DIM;
    const int E = in_sizes[5];
    const float* h  = (const float*)d_in[0];
    const float* W1 = (const float*)d_in[1];
    const float* b1 = (const float*)d_in[2];
    const float* W2 = (const float*)d_in[3];
    const float* b2 = (const float*)d_in[4];
    const int* src  = (const int*)d_in[5];
    const int* dst  = (const int*)d_in[6];
    float* out = (float*)d_out;

    const int NBINS  = (N + BIN_SIZE - 1) >> BIN_SHIFT;   // 98
    const int NCHUNK = (E + CHUNK - 1) / CHUNK;           // 391

    char* w = (char*)d_ws;
    size_t off = 0;
    auto alloc = [&](size_t bytes) -> void* {
        void* p = w + off;
        off += (bytes + 255) & ~(size_t)255;
        return p;
    };
    int* deg_in   = (int*)alloc((size_t)N * 4);
    int* deg_out  = (int*)alloc((size_t)N * 4);
    int* row_ptr  = (int*)alloc((size_t)(N + 1) * 4);
    int* cursor   = (int*)alloc((size_t)N * 4);
    int* bsum     = (int*)alloc(1024 * 4);
    float* rs_out = (float*)alloc((size_t)N * 4);
    float* rs_in  = (float*)alloc((size_t)N * 4);
    int* col      = (int*)alloc((size_t)E * 4);
    int* bboD     = (int*)alloc((size_t)NCHUNK * (NBINS + 1) * 4);
    int* bboS     = (int*)alloc((size_t)NCHUNK * (NBINS + 1) * 4);
    short* Wg     = (short*)alloc((size_t)8 * 8 * 64 * 8 * 2);   // 64 KB
    short* h1     = (short*)alloc((size_t)N * HID * 2);          // bf16
    float* x1     = (float*)alloc((size_t)N * HID * 4);          // fp32
    short* h2     = h1;                       // h1 dead after spmm1
    uint32_t* stD = (uint32_t*)x1;            // staging dead before spmm1 writes x1
    unsigned short* stS = (unsigned short*)(x1 + (size_t)E);

    int gN = (N + 255) / 256;
    int NB = (N + 1023) / 1024;

    hipMemsetAsync(deg_in, 0, (size_t)N * 4, stream);
    hipMemsetAsync(deg_out, 0, (size_t)N * 4, stream);
    k_wrepack<<<32, 256, 0, stream>>>(W1, Wg);
    k_binscatter<<<NCHUNK, 256, 0, stream>>>(src, dst, stD, stS, bboD, bboS, E, NBINS);
    k_deg_src<<<dim3(NBINS, GSPLIT), 256, 0, stream>>>(stS, bboS, deg_out, N, NCHUNK, NBINS);
    k_deg_dst<<<dim3(NBINS, GSPLIT), 256, 0, stream>>>(stD, bboD, deg_in, N, NCHUNK, NBINS);
    k_scan1<<<NB, 256, 0, stream>>>(deg_in, row_ptr, bsum, rs_in, N);
    k_scan2<<<1, 1024, 0, stream>>>(bsum, NB);
    k_scan3<<<gN, 256, 0, stream>>>(row_ptr, bsum, cursor, deg_out, rs_out, N, E);
    k_col<<<dim3(NBINS, GSPLIT), 256, 0, stream>>>(stD, bboD, cursor, col, N, NCHUNK, NBINS);
    k_gemm1<<<(N + 63) / 64, 256, 0, stream>>>(h, Wg, rs_out, h1, N);
    k_spmm1<<<(N + 3) / 4, 256, 0, stream>>>((const uint32_t*)h1, row_ptr, col, rs_in, b1, x1, N);
    k_gemm2<<<(N + 63) / 64, 256, 0, stream>>>(x1, W2, rs_out, h2, N);
    k_spmm2<<<(N + 3) / 4, 256, 0, stream>>>((const unsigned short*)h2, row_ptr, col, rs_in, b2, out, N);
}

// Round 5
// 567.696 us; speedup vs baseline: 1.9528x; 1.0938x over previous
//
#include <hip/hip_runtime.h>
#include <hip/hip_bf16.h>
#include <cstddef>
#include <cstdint>

#define IN_DIM 256
#define HID 128
#define OUT_DIM 40

#define CHUNK 8192      // edges per binscatter block (private staging region)
#define BIN_SHIFT 10    // 1024 nodes per bin
#define BIN_SIZE 1024
#define MAXB 128        // >= NBINS+1
#define GSPLIT 8        // blocks per bin for deg/col kernels

typedef __attribute__((ext_vector_type(8))) short short8;
typedef __attribute__((ext_vector_type(4))) float f32x4;
typedef __attribute__((ext_vector_type(2))) float f32x2;

__device__ inline short f2bf(float f) {
    __hip_bfloat16 b = __float2bfloat16(f);   // RNE
    return __builtin_bit_cast(short, b);
}
// feature permutation for h1/x1 storage: slot p holds feature (p>>3) + 16*(p&7).
// gemm1 packs lane-resident nt-values without LDS transpose; spmm1 (bias, x1 store)
// and gemm2 (W2 stage) apply the same permutation -> math unchanged.
__device__ inline int permf(int p) { return (p >> 3) + 16 * (p & 7); }

// ---------------- CSR build: chunk-private counting sort by dst/src bin ----------------
__global__ __launch_bounds__(256) void k_binscatter(const int* __restrict__ src, const int* __restrict__ dst,
                                                    uint32_t* __restrict__ stD, unsigned short* __restrict__ stS,
                                                    int* __restrict__ bboD, int* __restrict__ bboS,
                                                    int E, int NBINS) {
    __shared__ int hD[MAXB], hS[MAXB], cD[MAXB], cS[MAXB], sd[MAXB];
    int j = blockIdx.x, t = threadIdx.x;
    int base = j * CHUNK;
    int nE = min(CHUNK, E - base);
    int NB1 = NBINS + 1;
    for (int i = t; i < MAXB; i += 256) { hD[i] = 0; hS[i] = 0; }
    __syncthreads();
    for (int i = t; i < nE; i += 256) {
        atomicAdd(&hD[dst[base + i] >> BIN_SHIFT], 1);
        atomicAdd(&hS[src[base + i] >> BIN_SHIFT], 1);
    }
    __syncthreads();
    if (t < MAXB) sd[t] = hD[t];
    __syncthreads();
    for (int off = 1; off < MAXB; off <<= 1) {
        int x = 0;
        if (t < MAXB && t >= off) x = sd[t - off];
        __syncthreads();
        if (t < MAXB) sd[t] += x;
        __syncthreads();
    }
    if (t < MAXB) cD[t] = sd[t] - hD[t];
    if (t < NBINS) bboD[(size_t)j * NB1 + t] = sd[t] - hD[t];
    if (t == NBINS) bboD[(size_t)j * NB1 + NBINS] = nE;
    __syncthreads();
    if (t < MAXB) sd[t] = hS[t];
    __syncthreads();
    for (int off = 1; off < MAXB; off <<= 1) {
        int x = 0;
        if (t < MAXB && t >= off) x = sd[t - off];
        __syncthreads();
        if (t < MAXB) sd[t] += x;
        __syncthreads();
    }
    if (t < MAXB) cS[t] = sd[t] - hS[t];
    if (t < NBINS) bboS[(size_t)j * NB1 + t] = sd[t] - hS[t];
    if (t == NBINS) bboS[(size_t)j * NB1 + NBINS] = nE;
    __syncthreads();
    for (int i = t; i < nE; i += 256) {
        int s = src[base + i], d = dst[base + i];
        int pD = atomicAdd(&cD[d >> BIN_SHIFT], 1);
        stD[(size_t)base + pD] = ((uint32_t)(d & (BIN_SIZE - 1)) << 17) | (uint32_t)s;
        int pS = atomicAdd(&cS[s >> BIN_SHIFT], 1);
        stS[(size_t)base + pS] = (unsigned short)(s & (BIN_SIZE - 1));
    }
}

__global__ __launch_bounds__(256) void k_deg_dst(const uint32_t* __restrict__ stD, const int* __restrict__ bboD,
                                                 int* __restrict__ deg_in, int N, int nchunk, int NBINS) {
    __shared__ int hist[BIN_SIZE];
    int b = blockIdx.x, g = blockIdx.y, t = threadIdx.x;
    int wv = t >> 6, lane = t & 63;
    int NB1 = NBINS + 1;
    for (int i = t; i < BIN_SIZE; i += 256) hist[i] = 0;
    __syncthreads();
    for (int j = g * 4 + wv; j < nchunk; j += GSPLIT * 4) {
        int s = bboD[(size_t)j * NB1 + b], e = bboD[(size_t)j * NB1 + b + 1];
        const uint32_t* seg = stD + (size_t)j * CHUNK;
        for (int i = s + lane; i < e; i += 64)
            atomicAdd(&hist[seg[i] >> 17], 1);
    }
    __syncthreads();
    int base = b << BIN_SHIFT;
    for (int i = t; i < BIN_SIZE; i += 256) {
        int v = hist[i];
        if (v) atomicAdd(&deg_in[base + i], v);
    }
}

__global__ __launch_bounds__(256) void k_deg_src(const unsigned short* __restrict__ stS, const int* __restrict__ bboS,
                                                 int* __restrict__ deg_out, int N, int nchunk, int NBINS) {
    __shared__ int hist[BIN_SIZE];
    int b = blockIdx.x, g = blockIdx.y, t = threadIdx.x;
    int wv = t >> 6, lane = t & 63;
    int NB1 = NBINS + 1;
    for (int i = t; i < BIN_SIZE; i += 256) hist[i] = 0;
    __syncthreads();
    for (int j = g * 4 + wv; j < nchunk; j += GSPLIT * 4) {
        int s = bboS[(size_t)j * NB1 + b], e = bboS[(size_t)j * NB1 + b + 1];
        const unsigned short* seg = stS + (size_t)j * CHUNK;
        for (int i = s + lane; i < e; i += 64)
            atomicAdd(&hist[seg[i]], 1);
    }
    __syncthreads();
    int base = b << BIN_SHIFT;
    for (int i = t; i < BIN_SIZE; i += 256) {
        int v = hist[i];
        if (v) atomicAdd(&deg_out[base + i], v);
    }
}

__global__ __launch_bounds__(256) void k_col(const uint32_t* __restrict__ stD, const int* __restrict__ bboD,
                                             int* __restrict__ cursor, int* __restrict__ col,
                                             int N, int nchunk, int NBINS) {
    __shared__ int hist[BIN_SIZE];
    int b = blockIdx.x, g = blockIdx.y, t = threadIdx.x;
    int wv = t >> 6, lane = t & 63;
    int NB1 = NBINS + 1;
    for (int i = t; i < BIN_SIZE; i += 256) hist[i] = 0;
    __syncthreads();
    for (int j = g * 4 + wv; j < nchunk; j += GSPLIT * 4) {
        int s = bboD[(size_t)j * NB1 + b], e = bboD[(size_t)j * NB1 + b + 1];
        const uint32_t* seg = stD + (size_t)j * CHUNK;
        for (int i = s + lane; i < e; i += 64)
            atomicAdd(&hist[seg[i] >> 17], 1);
    }
    __syncthreads();
    int base = b << BIN_SHIFT;
    for (int i = t; i < BIN_SIZE; i += 256) {
        int v = hist[i];
        hist[i] = v ? atomicAdd(&cursor[base + i], v) : 0;
    }
    __syncthreads();
    for (int j = g * 4 + wv; j < nchunk; j += GSPLIT * 4) {
        int s = bboD[(size_t)j * NB1 + b], e = bboD[(size_t)j * NB1 + b + 1];
        const uint32_t* seg = stD + (size_t)j * CHUNK;
        for (int i = s + lane; i < e; i += 64) {
            uint32_t v = seg[i];
            int pos = atomicAdd(&hist[v >> 17], 1);
            col[pos] = (int)(v & 0x1FFFFu);
        }
    }
}

__global__ __launch_bounds__(256) void k_scan1(const int* __restrict__ deg, int* __restrict__ out,
                                               int* __restrict__ bsum, float* __restrict__ rs_in, int n) {
    __shared__ int sd[256];
    int t = threadIdx.x, b = blockIdx.x;
    int base = b * 1024 + t * 4;
    int v0 = 0, v1 = 0, v2 = 0, v3 = 0;
    if (base + 0 < n) v0 = deg[base + 0];
    if (base + 1 < n) v1 = deg[base + 1];
    if (base + 2 < n) v2 = deg[base + 2];
    if (base + 3 < n) v3 = deg[base + 3];
    if (base + 0 < n) rs_in[base + 0] = rsqrtf((float)max(v0, 1));
    if (base + 1 < n) rs_in[base + 1] = rsqrtf((float)max(v1, 1));
    if (base + 2 < n) rs_in[base + 2] = rsqrtf((float)max(v2, 1));
    if (base + 3 < n) rs_in[base + 3] = rsqrtf((float)max(v3, 1));
    int ts = v0 + v1 + v2 + v3;
    sd[t] = ts;
    __syncthreads();
    for (int off = 1; off < 256; off <<= 1) {
        int x = 0;
        if (t >= off) x = sd[t - off];
        __syncthreads();
        sd[t] += x;
        __syncthreads();
    }
    int excl = sd[t] - ts;
    if (base + 0 < n) out[base + 0] = excl;
    if (base + 1 < n) out[base + 1] = excl + v0;
    if (base + 2 < n) out[base + 2] = excl + v0 + v1;
    if (base + 3 < n) out[base + 3] = excl + v0 + v1 + v2;
    if (t == 255) bsum[b] = sd[255];
}

__global__ __launch_bounds__(1024) void k_scan2(int* __restrict__ bsum, int nb) {
    __shared__ int sd[1024];
    int t = threadIdx.x;
    int v = (t < nb) ? bsum[t] : 0;
    sd[t] = v;
    __syncthreads();
    for (int off = 1; off < 1024; off <<= 1) {
        int x = 0;
        if (t >= off) x = sd[t - off];
        __syncthreads();
        sd[t] += x;
        __syncthreads();
    }
    if (t < nb) bsum[t] = sd[t] - v;   // exclusive
}

__global__ __launch_bounds__(256) void k_scan3(int* __restrict__ row_ptr, const int* __restrict__ bsum,
                                               int* __restrict__ cursor, const int* __restrict__ deg_out,
                                               float* __restrict__ rs_out, int n, int E) {
    int i = blockIdx.x * 256 + threadIdx.x;
    if (i < n) {
        int v = row_ptr[i] + bsum[i >> 10];
        row_ptr[i] = v;
        cursor[i] = v;
        rs_out[i] = rsqrtf((float)max(deg_out[i], 1));
    }
    if (i == 0) row_ptr[n] = E;
}

// ---------------- W1 repack (once): fp32 [256][128] -> bf16 fragments [nt][ks][lane][8] ----------------
__global__ __launch_bounds__(256) void k_wrepack(const float* __restrict__ B, short* __restrict__ Wg) {
    int u = blockIdx.x * 256 + threadIdx.x;   // 8192 float4 units
    int k = u >> 5;                           // 0..255
    int n0 = (u & 31) * 4;
    float4 v = *(const float4*)(B + (size_t)k * HID + n0);
    int ks = k >> 5, quad = (k >> 3) & 3, j = k & 7;
    float vv[4] = {v.x, v.y, v.z, v.w};
#pragma unroll
    for (int e = 0; e < 4; ++e) {
        int n = n0 + e;
        int nt = n >> 4;
        int ln = (n & 15) | (quad << 4);
        Wg[(((nt * 8 + ks) * 64) + ln) * 8 + j] = f2bf(vv[e]);
    }
}

// ---------------- GEMM1 (bf16 MFMA): h1f = fp8((h @ W1) * rs_out[row]), permuted columns ----------------
__global__ __launch_bounds__(256) void k_gemm1(const float* __restrict__ A, const short* __restrict__ Wg,
                                               const float* __restrict__ rs_out, uint32_t* __restrict__ h1f, int M) {
    __shared__ short As[64 * 264];            // [row][k], k-pitch 264 (33 KB)
    int t = threadIdx.x;
    int lane = t & 63, wv = t >> 6;
    int block_row = blockIdx.x * 64;
#pragma unroll
    for (int i = 0; i < 16; ++i) {
        int u = t + i * 256;                  // 4096 float4 units
        int row = u >> 6, kq = (u & 63) * 4;
        int gr = block_row + row;
        float4 v = {0.f, 0.f, 0.f, 0.f};
        if (gr < M) v = *(const float4*)(A + (size_t)gr * IN_DIM + kq);
        short4 sv = {f2bf(v.x), f2bf(v.y), f2bf(v.z), f2bf(v.w)};
        *(short4*)&As[row * 264 + kq] = sv;
    }
    __syncthreads();
    f32x4 acc[8] = {};
    int arow = (wv * 16 + (lane & 15)) * 264 + (lane >> 4) * 8;
#pragma unroll
    for (int ks = 0; ks < 8; ++ks) {
        short8 a = *(short8*)&As[arow + ks * 32];
#pragma unroll
        for (int nt = 0; nt < 8; ++nt) {
            short8 b = *(const short8*)&Wg[(((nt * 8 + ks) * 64) + lane) * 8];
            acc[nt] = __builtin_amdgcn_mfma_f32_16x16x32_bf16(a, b, acc[nt], 0, 0, 0);
        }
    }
    // epilogue: lane packs its 8 nt-values per row into 2 dwords (fp8), stores dwordx2.
    // byte p of row holds feature permf(p) = (p>>3) + 16*(p&7); lane cl covers bytes cl*8..cl*8+7.
    int quad = lane >> 4, cl = lane & 15;
#pragma unroll
    for (int r = 0; r < 4; ++r) {
        int gr = block_row + wv * 16 + quad * 4 + r;
        if (gr >= M) continue;
        float sc = rs_out[gr];
        int d0 = __builtin_amdgcn_cvt_pk_fp8_f32(acc[0][r] * sc, acc[1][r] * sc, 0, false);
        d0 = __builtin_amdgcn_cvt_pk_fp8_f32(acc[2][r] * sc, acc[3][r] * sc, d0, true);
        int d1 = __builtin_amdgcn_cvt_pk_fp8_f32(acc[4][r] * sc, acc[5][r] * sc, 0, false);
        d1 = __builtin_amdgcn_cvt_pk_fp8_f32(acc[6][r] * sc, acc[7][r] * sc, d1, true);
        uint2 dd = make_uint2((uint32_t)d0, (uint32_t)d1);
        *(uint2*)((char*)h1f + (size_t)gr * 128 + cl * 8) = dd;
    }
}

// ---------------- SpMM1 (fp8): x1[d] = relu(rs_in[d] * sum h1f[col[e]] + b1), permuted ----------------
// one wave per dst row; half-wave per edge (128 B row = 32 dwords), 2 edges per wave-load.
__global__ __launch_bounds__(256) void k_spmm1(const uint32_t* __restrict__ h1f, const int* __restrict__ rp,
                                               const int* __restrict__ col, const float* __restrict__ rs_in,
                                               const float* __restrict__ b1, float* __restrict__ x1, int n) {
    int w = (blockIdx.x * 256 + threadIdx.x) >> 6;
    int lane = threadIdx.x & 63;
    if (w >= n) return;
    int half = lane >> 5, sl = lane & 31;
    int s = rp[w], e = rp[w + 1];
    float4 acc = {0.f, 0.f, 0.f, 0.f};
    int i = s;
    for (; i + 4 <= e; i += 4) {
        int cA = col[i + half];
        int cB = col[i + 2 + half];
        uint32_t uA = h1f[(size_t)cA * 32 + sl];
        uint32_t uB = h1f[(size_t)cB * 32 + sl];
        f32x2 a0 = __builtin_amdgcn_cvt_pk_f32_fp8(uA, false);
        f32x2 a1 = __builtin_amdgcn_cvt_pk_f32_fp8(uA, true);
        f32x2 b0 = __builtin_amdgcn_cvt_pk_f32_fp8(uB, false);
        f32x2 b1v = __builtin_amdgcn_cvt_pk_f32_fp8(uB, true);
        acc.x += a0.x + b0.x; acc.y += a0.y + b0.y;
        acc.z += a1.x + b1v.x; acc.w += a1.y + b1v.y;
    }
    if (i + 2 <= e) {
        int c = col[i + half];
        uint32_t u = h1f[(size_t)c * 32 + sl];
        f32x2 a0 = __builtin_amdgcn_cvt_pk_f32_fp8(u, false);
        f32x2 a1 = __builtin_amdgcn_cvt_pk_f32_fp8(u, true);
        acc.x += a0.x; acc.y += a0.y; acc.z += a1.x; acc.w += a1.y;
        i += 2;
    }
    if (i < e) {
        int c = col[i];
        uint32_t u = h1f[(size_t)c * 32 + sl];
        float m = (half == 0) ? 1.f : 0.f;
        f32x2 a0 = __builtin_amdgcn_cvt_pk_f32_fp8(u, false);
        f32x2 a1 = __builtin_amdgcn_cvt_pk_f32_fp8(u, true);
        acc.x = fmaf(a0.x, m, acc.x); acc.y = fmaf(a0.y, m, acc.y);
        acc.z = fmaf(a1.x, m, acc.z); acc.w = fmaf(a1.y, m, acc.w);
    }
    acc.x += __shfl_xor(acc.x, 32, 64);
    acc.y += __shfl_xor(acc.y, 32, 64);
    acc.z += __shfl_xor(acc.z, 32, 64);
    acc.w += __shfl_xor(acc.w, 32, 64);
    if (half == 0) {
        float sc = rs_in[w];
        int q = sl * 4;
        float4 o;
        o.x = fmaxf(fmaf(acc.x, sc, b1[permf(q + 0)]), 0.f);
        o.y = fmaxf(fmaf(acc.y, sc, b1[permf(q + 1)]), 0.f);
        o.z = fmaxf(fmaf(acc.z, sc, b1[permf(q + 2)]), 0.f);
        o.w = fmaxf(fmaf(acc.w, sc, b1[permf(q + 3)]), 0.f);
        *(float4*)(x1 + (size_t)w * HID + q) = o;
    }
}

// ---------------- GEMM2: h2f = fp8((x1 @ W2) * rs_out[row])  (x1 is column-permuted) ----------------
__global__ __launch_bounds__(256) void k_gemm2(const float* __restrict__ A, const float* __restrict__ B,
                                               const float* __restrict__ rs_out, unsigned char* __restrict__ h2f,
                                               int M) {
    __shared__ float As[64 * 132];       // [row][k], k-pitch 132
    __shared__ float Wt[OUT_DIM * 132];  // [col][k], k permuted to match x1
    __shared__ unsigned char hs[64 * 40];
    int t = threadIdx.x;
    int base_row = blockIdx.x * 64;
    for (int i = 0; i < 20; ++i) {
        int flat = t + i * 256;          // 5120
        int q = flat / 40, c = flat - q * 40;
        Wt[c * 132 + q] = B[(size_t)permf(q) * OUT_DIM + c];
    }
#pragma unroll
    for (int i = 0; i < 8; ++i) {
        int u = t + i * 256;
        int row = u >> 5, kc = (u & 31) * 4;
        int gr = base_row + row;
        float4 v = {0.f, 0.f, 0.f, 0.f};
        if (gr < M) v = *(const float4*)(A + (size_t)gr * HID + kc);
        *(float4*)&As[row * 132 + kc] = v;
    }
    __syncthreads();
    int cg = t & 7, rg = t >> 3;
    int c0 = cg * 5, r0 = rg * 2;
    float acc[2][5] = {};
    for (int k = 0; k < HID; k += 4) {
        float4 a0 = *(const float4*)&As[r0 * 132 + k];
        float4 a1 = *(const float4*)&As[(r0 + 1) * 132 + k];
#pragma unroll
        for (int j = 0; j < 5; ++j) {
            float4 wv = *(const float4*)&Wt[(c0 + j) * 132 + k];
            acc[0][j] = fmaf(a0.x, wv.x, acc[0][j]);
            acc[0][j] = fmaf(a0.y, wv.y, acc[0][j]);
            acc[0][j] = fmaf(a0.z, wv.z, acc[0][j]);
            acc[0][j] = fmaf(a0.w, wv.w, acc[0][j]);
            acc[1][j] = fmaf(a1.x, wv.x, acc[1][j]);
            acc[1][j] = fmaf(a1.y, wv.y, acc[1][j]);
            acc[1][j] = fmaf(a1.z, wv.z, acc[1][j]);
            acc[1][j] = fmaf(a1.w, wv.w, acc[1][j]);
        }
    }
#pragma unroll
    for (int ri = 0; ri < 2; ++ri) {
        int r = base_row + r0 + ri;
        if (r < M) {
            float sc = rs_out[r];
            float v0 = acc[ri][0] * sc, v1 = acc[ri][1] * sc, v2 = acc[ri][2] * sc;
            float v3 = acc[ri][3] * sc, v4 = acc[ri][4] * sc;
            int p0 = __builtin_amdgcn_cvt_pk_fp8_f32(v0, v1, 0, false);
            int p1 = __builtin_amdgcn_cvt_pk_fp8_f32(v2, v3, 0, false);
            int p2 = __builtin_amdgcn_cvt_pk_fp8_f32(v4, v4, 0, false);
            unsigned char* hp = &hs[(r0 + ri) * 40 + c0];
            hp[0] = (unsigned char)(p0 & 0xff);
            hp[1] = (unsigned char)((p0 >> 8) & 0xff);
            hp[2] = (unsigned char)(p1 & 0xff);
            hp[3] = (unsigned char)((p1 >> 8) & 0xff);
            hp[4] = (unsigned char)(p2 & 0xff);
        }
    }
    __syncthreads();
    int vr = min(64, M - base_row);
    int nd = vr * 10;                    // dwords to copy (40 B rows, contiguous)
    const uint32_t* hw = (const uint32_t*)hs;
    for (int idx = t; idx < nd; idx += 256)
        *(uint32_t*)(h2f + (size_t)base_row * 40 + (size_t)idx * 4) = hw[idx];
}

// ---------------- SpMM2 (fp8) + bias + log_softmax ----------------
// one wave per dst row; 10 lanes per edge (40 B row = 10 dwords), 6 edges per wave-load.
__global__ __launch_bounds__(256) void k_spmm2(const unsigned char* __restrict__ h2f, const int* __restrict__ rp,
                                               const int* __restrict__ col, const float* __restrict__ rs_in,
                                               const float* __restrict__ b2, float* __restrict__ out, int n) {
    int w = (blockIdx.x * 256 + threadIdx.x) >> 6;
    int lane = threadIdx.x & 63;
    if (w >= n) return;
    int grp = lane / 10;                 // 0..6 (lanes 60..63 -> 6, masked out)
    int dw = lane - grp * 10;            // 0..9
    int grpc = (grp < 6) ? grp : 0;
    float m6 = (grp < 6) ? 1.f : 0.f;
    int s = rp[w], e = rp[w + 1];
    float4 acc = {0.f, 0.f, 0.f, 0.f};
    int i = s;
    for (; i + 6 <= e; i += 6) {
        int c = col[i + grpc];
        uint32_t u = *(const uint32_t*)(h2f + (size_t)c * 40 + dw * 4);
        f32x2 lo = __builtin_amdgcn_cvt_pk_f32_fp8(u, false);
        f32x2 hi = __builtin_amdgcn_cvt_pk_f32_fp8(u, true);
        acc.x = fmaf(lo.x, m6, acc.x);
        acc.y = fmaf(lo.y, m6, acc.y);
        acc.z = fmaf(hi.x, m6, acc.z);
        acc.w = fmaf(hi.y, m6, acc.w);
    }
    int r = e - i;
    if (r > 0) {
        int gg = (grpc < r) ? grpc : (r - 1);
        float mm = (grp < r) ? 1.f : 0.f;
        int c = col[i + gg];
        uint32_t u = *(const uint32_t*)(h2f + (size_t)c * 40 + dw * 4);
        f32x2 lo = __builtin_amdgcn_cvt_pk_f32_fp8(u, false);
        f32x2 hi = __builtin_amdgcn_cvt_pk_f32_fp8(u, true);
        acc.x = fmaf(lo.x, mm, acc.x);
        acc.y = fmaf(lo.y, mm, acc.y);
        acc.z = fmaf(hi.x, mm, acc.z);
        acc.w = fmaf(hi.y, mm, acc.w);
    }
    // reduce 6 edge-groups -> lanes 0..9
    acc.x += __shfl(acc.x, lane + 30, 64);
    acc.y += __shfl(acc.y, lane + 30, 64);
    acc.z += __shfl(acc.z, lane + 30, 64);
    acc.w += __shfl(acc.w, lane + 30, 64);
    float4 v;
    v.x = acc.x + __shfl(acc.x, lane + 10, 64) + __shfl(acc.x, lane + 20, 64);
    v.y = acc.y + __shfl(acc.y, lane + 10, 64) + __shfl(acc.y, lane + 20, 64);
    v.z = acc.z + __shfl(acc.z, lane + 10, 64) + __shfl(acc.z, lane + 20, 64);
    v.w = acc.w + __shfl(acc.w, lane + 10, 64) + __shfl(acc.w, lane + 20, 64);
    bool act = lane < 10;
    float sc = rs_in[w];
    int bi = act ? lane * 4 : 0;
    float4 bb = *(const float4*)(b2 + bi);
    float4 val;
    val.x = fmaf(v.x, sc, bb.x);
    val.y = fmaf(v.y, sc, bb.y);
    val.z = fmaf(v.z, sc, bb.z);
    val.w = fmaf(v.w, sc, bb.w);
    float pm = act ? fmaxf(fmaxf(val.x, val.y), fmaxf(val.z, val.w)) : -INFINITY;
    for (int o = 8; o; o >>= 1) pm = fmaxf(pm, __shfl_xor(pm, o, 16));
    float ex = act ? (expf(val.x - pm) + expf(val.y - pm) + expf(val.z - pm) + expf(val.w - pm)) : 0.f;
    float ssum = ex;
    for (int o = 8; o; o >>= 1) ssum += __shfl_xor(ssum, o, 16);
    if (act) {
        float l = pm + logf(ssum);
        float4 o4 = {val.x - l, val.y - l, val.z - l, val.w - l};
        *(float4*)(out + (size_t)w * OUT_DIM + lane * 4) = o4;
    }
}

// ---------------- launch ----------------

extern "C" void kernel_launch(void* const* d_in, const int* in_sizes, int n_in,
                              void* d_out, int out_size, void* d_ws, size_t ws_size,
                              hipStream_t stream) {
    const int N = in_sizes[0] / IN_DIM;
    const int E = in_sizes[5];
    const float* h  = (const float*)d_in[0];
    const float* W1 = (const float*)d_in[1];
    const float* b1 = (const float*)d_in[2];
    const float* W2 = (const float*)d_in[3];
    const float* b2 = (const float*)d_in[4];
    const int* src  = (const int*)d_in[5];
    const int* dst  = (const int*)d_in[6];
    float* out = (float*)d_out;

    const int NBINS  = (N + BIN_SIZE - 1) >> BIN_SHIFT;   // 98
    const int NCHUNK = (E + CHUNK - 1) / CHUNK;           // 391

    char* w = (char*)d_ws;
    size_t off = 0;
    auto alloc = [&](size_t bytes) -> void* {
        void* p = w + off;
        off += (bytes + 255) & ~(size_t)255;
        return p;
    };
    int* deg_in   = (int*)alloc((size_t)N * 4);
    int* deg_out  = (int*)alloc((size_t)N * 4);
    int* row_ptr  = (int*)alloc((size_t)(N + 1) * 4);
    int* cursor   = (int*)alloc((size_t)N * 4);
    int* bsum     = (int*)alloc(1024 * 4);
    float* rs_out = (float*)alloc((size_t)N * 4);
    float* rs_in  = (float*)alloc((size_t)N * 4);
    int* col      = (int*)alloc((size_t)E * 4);
    int* bboD     = (int*)alloc((size_t)NCHUNK * (NBINS + 1) * 4);
    int* bboS     = (int*)alloc((size_t)NCHUNK * (NBINS + 1) * 4);
    short* Wg     = (short*)alloc((size_t)8 * 8 * 64 * 8 * 2);    // 64 KB
    uint32_t* h1f = (uint32_t*)alloc((size_t)N * HID);            // fp8, 12.8 MB
    unsigned char* h2f = (unsigned char*)alloc((size_t)N * OUT_DIM);  // fp8, 4 MB
    float* x1     = (float*)alloc((size_t)N * HID * 4);           // fp32 (permuted), 51.2 MB
    uint32_t* stD = (uint32_t*)x1;            // staging dead before spmm1 writes x1
    unsigned short* stS = (unsigned short*)(x1 + (size_t)E);

    int gN = (N + 255) / 256;
    int NB = (N + 1023) / 1024;

    hipMemsetAsync(deg_in, 0, (size_t)N * 4, stream);
    hipMemsetAsync(deg_out, 0, (size_t)N * 4, stream);
    k_wrepack<<<32, 256, 0, stream>>>(W1, Wg);
    k_binscatter<<<NCHUNK, 256, 0, stream>>>(src, dst, stD, stS, bboD, bboS, E, NBINS);
    k_deg_src<<<dim3(NBINS, GSPLIT), 256, 0, stream>>>(stS, bboS, deg_out, N, NCHUNK, NBINS);
    k_deg_dst<<<dim3(NBINS, GSPLIT), 256, 0, stream>>>(stD, bboD, deg_in, N, NCHUNK, NBINS);
    k_scan1<<<NB, 256, 0, stream>>>(deg_in, row_ptr, bsum, rs_in, N);
    k_scan2<<<1, 1024, 0, stream>>>(bsum, NB);
    k_scan3<<<gN, 256, 0, stream>>>(row_ptr, bsum, cursor, deg_out, rs_out, N, E);
    k_col<<<dim3(NBINS, GSPLIT), 256, 0, stream>>>(stD, bboD, cursor, col, N, NCHUNK, NBINS);
    k_gemm1<<<(N + 63) / 64, 256, 0, stream>>>(h, Wg, rs_out, h1f, N);
    k_spmm1<<<(N + 3) / 4, 256, 0, stream>>>(h1f, row_ptr, col, rs_in, b1, x1, N);
    k_gemm2<<<(N + 63) / 64, 256, 0, stream>>>(x1, W2, rs_out, h2f, N);
    k_spmm2<<<(N + 3) / 4, 256, 0, stream>>>(h2f, row_ptr, col, rs_in, b2, out, N);
}

// Round 6
// 528.441 us; speedup vs baseline: 2.0979x; 1.0743x over previous
//
#include <hip/hip_runtime.h>
#include <hip/hip_bf16.h>
#include <cstddef>
#include <cstdint>

#define IN_DIM 256
#define HID 128
#define OUT_DIM 40

#define CHUNK 8192      // edges per binscatter block (private staging region)
#define BIN_SHIFT 10    // 1024 nodes per bin
#define BIN_SIZE 1024
#define MAXB 128        // >= NBINS+1
#define GSPLIT 8        // blocks per bin for deg/col kernels

typedef __attribute__((ext_vector_type(8))) short short8;
typedef __attribute__((ext_vector_type(4))) float f32x4;
typedef __attribute__((ext_vector_type(2))) float f32x2;

__device__ inline short f2bf(float f) {
    __hip_bfloat16 b = __float2bfloat16(f);   // RNE
    return __builtin_bit_cast(short, b);
}
__device__ inline float bf2f(unsigned short u) {
    unsigned int v = (unsigned int)u << 16;
    return __builtin_bit_cast(float, v);
}
// feature permutation for h1/x1 storage: slot p holds feature (p>>3) + 16*(p&7).
__device__ inline int permf(int p) { return (p >> 3) + 16 * (p & 7); }

// ---------------- CSR build: chunk-private counting sort by dst/src bin ----------------
__global__ __launch_bounds__(256) void k_binscatter(const int* __restrict__ src, const int* __restrict__ dst,
                                                    uint32_t* __restrict__ stD, unsigned short* __restrict__ stS,
                                                    int* __restrict__ bboD, int* __restrict__ bboS,
                                                    int E, int NBINS) {
    __shared__ int hD[MAXB], hS[MAXB], cD[MAXB], cS[MAXB], sd[MAXB];
    int j = blockIdx.x, t = threadIdx.x;
    int base = j * CHUNK;
    int nE = min(CHUNK, E - base);
    int NB1 = NBINS + 1;
    for (int i = t; i < MAXB; i += 256) { hD[i] = 0; hS[i] = 0; }
    __syncthreads();
    for (int i = t; i < nE; i += 256) {
        atomicAdd(&hD[dst[base + i] >> BIN_SHIFT], 1);
        atomicAdd(&hS[src[base + i] >> BIN_SHIFT], 1);
    }
    __syncthreads();
    if (t < MAXB) sd[t] = hD[t];
    __syncthreads();
    for (int off = 1; off < MAXB; off <<= 1) {
        int x = 0;
        if (t < MAXB && t >= off) x = sd[t - off];
        __syncthreads();
        if (t < MAXB) sd[t] += x;
        __syncthreads();
    }
    if (t < MAXB) cD[t] = sd[t] - hD[t];
    if (t < NBINS) bboD[(size_t)j * NB1 + t] = sd[t] - hD[t];
    if (t == NBINS) bboD[(size_t)j * NB1 + NBINS] = nE;
    __syncthreads();
    if (t < MAXB) sd[t] = hS[t];
    __syncthreads();
    for (int off = 1; off < MAXB; off <<= 1) {
        int x = 0;
        if (t < MAXB && t >= off) x = sd[t - off];
        __syncthreads();
        if (t < MAXB) sd[t] += x;
        __syncthreads();
    }
    if (t < MAXB) cS[t] = sd[t] - hS[t];
    if (t < NBINS) bboS[(size_t)j * NB1 + t] = sd[t] - hS[t];
    if (t == NBINS) bboS[(size_t)j * NB1 + NBINS] = nE;
    __syncthreads();
    for (int i = t; i < nE; i += 256) {
        int s = src[base + i], d = dst[base + i];
        int pD = atomicAdd(&cD[d >> BIN_SHIFT], 1);
        stD[(size_t)base + pD] = ((uint32_t)(d & (BIN_SIZE - 1)) << 17) | (uint32_t)s;
        int pS = atomicAdd(&cS[s >> BIN_SHIFT], 1);
        stS[(size_t)base + pS] = (unsigned short)(s & (BIN_SIZE - 1));
    }
}

__global__ __launch_bounds__(256) void k_deg_dst(const uint32_t* __restrict__ stD, const int* __restrict__ bboD,
                                                 int* __restrict__ deg_in, int N, int nchunk, int NBINS) {
    __shared__ int hist[BIN_SIZE];
    int b = blockIdx.x, g = blockIdx.y, t = threadIdx.x;
    int wv = t >> 6, lane = t & 63;
    int NB1 = NBINS + 1;
    for (int i = t; i < BIN_SIZE; i += 256) hist[i] = 0;
    __syncthreads();
    for (int j = g * 4 + wv; j < nchunk; j += GSPLIT * 4) {
        int s = bboD[(size_t)j * NB1 + b], e = bboD[(size_t)j * NB1 + b + 1];
        const uint32_t* seg = stD + (size_t)j * CHUNK;
        for (int i = s + lane; i < e; i += 64)
            atomicAdd(&hist[seg[i] >> 17], 1);
    }
    __syncthreads();
    int base = b << BIN_SHIFT;
    for (int i = t; i < BIN_SIZE; i += 256) {
        int v = hist[i];
        if (v) atomicAdd(&deg_in[base + i], v);
    }
}

__global__ __launch_bounds__(256) void k_deg_src(const unsigned short* __restrict__ stS, const int* __restrict__ bboS,
                                                 int* __restrict__ deg_out, int N, int nchunk, int NBINS) {
    __shared__ int hist[BIN_SIZE];
    int b = blockIdx.x, g = blockIdx.y, t = threadIdx.x;
    int wv = t >> 6, lane = t & 63;
    int NB1 = NBINS + 1;
    for (int i = t; i < BIN_SIZE; i += 256) hist[i] = 0;
    __syncthreads();
    for (int j = g * 4 + wv; j < nchunk; j += GSPLIT * 4) {
        int s = bboS[(size_t)j * NB1 + b], e = bboS[(size_t)j * NB1 + b + 1];
        const unsigned short* seg = stS + (size_t)j * CHUNK;
        for (int i = s + lane; i < e; i += 64)
            atomicAdd(&hist[seg[i]], 1);
    }
    __syncthreads();
    int base = b << BIN_SHIFT;
    for (int i = t; i < BIN_SIZE; i += 256) {
        int v = hist[i];
        if (v) atomicAdd(&deg_out[base + i], v);
    }
}

__global__ __launch_bounds__(256) void k_col(const uint32_t* __restrict__ stD, const int* __restrict__ bboD,
                                             int* __restrict__ cursor, int* __restrict__ col,
                                             int N, int nchunk, int NBINS) {
    __shared__ int hist[BIN_SIZE];
    int b = blockIdx.x, g = blockIdx.y, t = threadIdx.x;
    int wv = t >> 6, lane = t & 63;
    int NB1 = NBINS + 1;
    for (int i = t; i < BIN_SIZE; i += 256) hist[i] = 0;
    __syncthreads();
    for (int j = g * 4 + wv; j < nchunk; j += GSPLIT * 4) {
        int s = bboD[(size_t)j * NB1 + b], e = bboD[(size_t)j * NB1 + b + 1];
        const uint32_t* seg = stD + (size_t)j * CHUNK;
        for (int i = s + lane; i < e; i += 64)
            atomicAdd(&hist[seg[i] >> 17], 1);
    }
    __syncthreads();
    int base = b << BIN_SHIFT;
    for (int i = t; i < BIN_SIZE; i += 256) {
        int v = hist[i];
        hist[i] = v ? atomicAdd(&cursor[base + i], v) : 0;
    }
    __syncthreads();
    for (int j = g * 4 + wv; j < nchunk; j += GSPLIT * 4) {
        int s = bboD[(size_t)j * NB1 + b], e = bboD[(size_t)j * NB1 + b + 1];
        const uint32_t* seg = stD + (size_t)j * CHUNK;
        for (int i = s + lane; i < e; i += 64) {
            uint32_t v = seg[i];
            int pos = atomicAdd(&hist[v >> 17], 1);
            col[pos] = (int)(v & 0x1FFFFu);
        }
    }
}

__global__ __launch_bounds__(256) void k_scan1(const int* __restrict__ deg, int* __restrict__ out,
                                               int* __restrict__ bsum, float* __restrict__ rs_in, int n) {
    __shared__ int sd[256];
    int t = threadIdx.x, b = blockIdx.x;
    int base = b * 1024 + t * 4;
    int v0 = 0, v1 = 0, v2 = 0, v3 = 0;
    if (base + 0 < n) v0 = deg[base + 0];
    if (base + 1 < n) v1 = deg[base + 1];
    if (base + 2 < n) v2 = deg[base + 2];
    if (base + 3 < n) v3 = deg[base + 3];
    if (base + 0 < n) rs_in[base + 0] = rsqrtf((float)max(v0, 1));
    if (base + 1 < n) rs_in[base + 1] = rsqrtf((float)max(v1, 1));
    if (base + 2 < n) rs_in[base + 2] = rsqrtf((float)max(v2, 1));
    if (base + 3 < n) rs_in[base + 3] = rsqrtf((float)max(v3, 1));
    int ts = v0 + v1 + v2 + v3;
    sd[t] = ts;
    __syncthreads();
    for (int off = 1; off < 256; off <<= 1) {
        int x = 0;
        if (t >= off) x = sd[t - off];
        __syncthreads();
        sd[t] += x;
        __syncthreads();
    }
    int excl = sd[t] - ts;
    if (base + 0 < n) out[base + 0] = excl;
    if (base + 1 < n) out[base + 1] = excl + v0;
    if (base + 2 < n) out[base + 2] = excl + v0 + v1;
    if (base + 3 < n) out[base + 3] = excl + v0 + v1 + v2;
    if (t == 255) bsum[b] = sd[255];
}

__global__ __launch_bounds__(1024) void k_scan2(int* __restrict__ bsum, int nb) {
    __shared__ int sd[1024];
    int t = threadIdx.x;
    int v = (t < nb) ? bsum[t] : 0;
    sd[t] = v;
    __syncthreads();
    for (int off = 1; off < 1024; off <<= 1) {
        int x = 0;
        if (t >= off) x = sd[t - off];
        __syncthreads();
        sd[t] += x;
        __syncthreads();
    }
    if (t < nb) bsum[t] = sd[t] - v;   // exclusive
}

__global__ __launch_bounds__(256) void k_scan3(int* __restrict__ row_ptr, const int* __restrict__ bsum,
                                               int* __restrict__ cursor, const int* __restrict__ deg_out,
                                               float* __restrict__ rs_out, int n, int E) {
    int i = blockIdx.x * 256 + threadIdx.x;
    if (i < n) {
        int v = row_ptr[i] + bsum[i >> 10];
        row_ptr[i] = v;
        cursor[i] = v;
        rs_out[i] = rsqrtf((float)max(deg_out[i], 1));
    }
    if (i == 0) row_ptr[n] = E;
}

// ---------------- W1 repack (once): fp32 [256][128] -> bf16 fragments [nt][ks][lane][8] ----------------
__global__ __launch_bounds__(256) void k_wrepack(const float* __restrict__ B, short* __restrict__ Wg) {
    int u = blockIdx.x * 256 + threadIdx.x;   // 8192 float4 units
    int k = u >> 5;                           // 0..255
    int n0 = (u & 31) * 4;
    float4 v = *(const float4*)(B + (size_t)k * HID + n0);
    int ks = k >> 5, quad = (k >> 3) & 3, j = k & 7;
    float vv[4] = {v.x, v.y, v.z, v.w};
#pragma unroll
    for (int e = 0; e < 4; ++e) {
        int n = n0 + e;
        int nt = n >> 4;
        int ln = (n & 15) | (quad << 4);
        Wg[(((nt * 8 + ks) * 64) + ln) * 8 + j] = f2bf(vv[e]);
    }
}

// ---------------- GEMM1 (bf16 MFMA): h1f = fp8((h @ W1) * rs_out[row]), permuted columns ----------------
__global__ __launch_bounds__(256) void k_gemm1(const float* __restrict__ A, const short* __restrict__ Wg,
                                               const float* __restrict__ rs_out, uint32_t* __restrict__ h1f, int M) {
    __shared__ short As[64 * 264];            // [row][k], k-pitch 264 (33 KB)
    int t = threadIdx.x;
    int lane = t & 63, wv = t >> 6;
    int block_row = blockIdx.x * 64;
#pragma unroll
    for (int i = 0; i < 16; ++i) {
        int u = t + i * 256;                  // 4096 float4 units
        int row = u >> 6, kq = (u & 63) * 4;
        int gr = block_row + row;
        float4 v = {0.f, 0.f, 0.f, 0.f};
        if (gr < M) v = *(const float4*)(A + (size_t)gr * IN_DIM + kq);
        short4 sv = {f2bf(v.x), f2bf(v.y), f2bf(v.z), f2bf(v.w)};
        *(short4*)&As[row * 264 + kq] = sv;
    }
    __syncthreads();
    f32x4 acc[8] = {};
    int arow = (wv * 16 + (lane & 15)) * 264 + (lane >> 4) * 8;
#pragma unroll
    for (int ks = 0; ks < 8; ++ks) {
        short8 a = *(short8*)&As[arow + ks * 32];
#pragma unroll
        for (int nt = 0; nt < 8; ++nt) {
            short8 b = *(const short8*)&Wg[(((nt * 8 + ks) * 64) + lane) * 8];
            acc[nt] = __builtin_amdgcn_mfma_f32_16x16x32_bf16(a, b, acc[nt], 0, 0, 0);
        }
    }
    int quad = lane >> 4, cl = lane & 15;
#pragma unroll
    for (int r = 0; r < 4; ++r) {
        int gr = block_row + wv * 16 + quad * 4 + r;
        if (gr >= M) continue;
        float sc = rs_out[gr];
        int d0 = __builtin_amdgcn_cvt_pk_fp8_f32(acc[0][r] * sc, acc[1][r] * sc, 0, false);
        d0 = __builtin_amdgcn_cvt_pk_fp8_f32(acc[2][r] * sc, acc[3][r] * sc, d0, true);
        int d1 = __builtin_amdgcn_cvt_pk_fp8_f32(acc[4][r] * sc, acc[5][r] * sc, 0, false);
        d1 = __builtin_amdgcn_cvt_pk_fp8_f32(acc[6][r] * sc, acc[7][r] * sc, d1, true);
        uint2 dd = make_uint2((uint32_t)d0, (uint32_t)d1);
        *(uint2*)((char*)h1f + (size_t)gr * 128 + cl * 8) = dd;
    }
}

// ---------------- SpMM1 (fp8, MLP): 8 lanes/edge x dwordx4; col batch-prefetch via shfl ----------------
// x1 output is bf16, permuted slots (2 feats per dword).
__global__ __launch_bounds__(256) void k_spmm1(const uint4* __restrict__ h1f4, const int* __restrict__ rp,
                                               const int* __restrict__ col, const float* __restrict__ rs_in,
                                               const float* __restrict__ b1, uint32_t* __restrict__ x1b, int n) {
    int w = (blockIdx.x * 256 + threadIdx.x) >> 6;
    int lane = threadIdx.x & 63;
    if (w >= n) return;
    int grp = lane >> 3, ql = lane & 7;
    int s = rp[w], e = rp[w + 1];
    float acc[16] = {};
    int i = s;
    while (i < e) {
        int cnt = min(64, e - i);
        int cl = (lane < cnt) ? lane : cnt - 1;
        int cidx = col[i + cl];
        for (int it = 0; it < cnt; it += 16) {
            int eA = it + grp, eB = it + 8 + grp;
            int cA = __shfl(cidx, eA, 64);
            int cB = __shfl(cidx, eB & 63, 64);
            float mA = (eA < cnt) ? 1.f : 0.f;
            float mB = (eB < cnt) ? 1.f : 0.f;
            uint4 uA = h1f4[(size_t)cA * 8 + ql];
            uint4 uB = h1f4[(size_t)cB * 8 + ql];
            {
                f32x2 p0 = __builtin_amdgcn_cvt_pk_f32_fp8(uA.x, false);
                f32x2 p1 = __builtin_amdgcn_cvt_pk_f32_fp8(uA.x, true);
                f32x2 p2 = __builtin_amdgcn_cvt_pk_f32_fp8(uA.y, false);
                f32x2 p3 = __builtin_amdgcn_cvt_pk_f32_fp8(uA.y, true);
                f32x2 p4 = __builtin_amdgcn_cvt_pk_f32_fp8(uA.z, false);
                f32x2 p5 = __builtin_amdgcn_cvt_pk_f32_fp8(uA.z, true);
                f32x2 p6 = __builtin_amdgcn_cvt_pk_f32_fp8(uA.w, false);
                f32x2 p7 = __builtin_amdgcn_cvt_pk_f32_fp8(uA.w, true);
                acc[0]  = fmaf(p0.x, mA, acc[0]);  acc[1]  = fmaf(p0.y, mA, acc[1]);
                acc[2]  = fmaf(p1.x, mA, acc[2]);  acc[3]  = fmaf(p1.y, mA, acc[3]);
                acc[4]  = fmaf(p2.x, mA, acc[4]);  acc[5]  = fmaf(p2.y, mA, acc[5]);
                acc[6]  = fmaf(p3.x, mA, acc[6]);  acc[7]  = fmaf(p3.y, mA, acc[7]);
                acc[8]  = fmaf(p4.x, mA, acc[8]);  acc[9]  = fmaf(p4.y, mA, acc[9]);
                acc[10] = fmaf(p5.x, mA, acc[10]); acc[11] = fmaf(p5.y, mA, acc[11]);
                acc[12] = fmaf(p6.x, mA, acc[12]); acc[13] = fmaf(p6.y, mA, acc[13]);
                acc[14] = fmaf(p7.x, mA, acc[14]); acc[15] = fmaf(p7.y, mA, acc[15]);
            }
            {
                f32x2 p0 = __builtin_amdgcn_cvt_pk_f32_fp8(uB.x, false);
                f32x2 p1 = __builtin_amdgcn_cvt_pk_f32_fp8(uB.x, true);
                f32x2 p2 = __builtin_amdgcn_cvt_pk_f32_fp8(uB.y, false);
                f32x2 p3 = __builtin_amdgcn_cvt_pk_f32_fp8(uB.y, true);
                f32x2 p4 = __builtin_amdgcn_cvt_pk_f32_fp8(uB.z, false);
                f32x2 p5 = __builtin_amdgcn_cvt_pk_f32_fp8(uB.z, true);
                f32x2 p6 = __builtin_amdgcn_cvt_pk_f32_fp8(uB.w, false);
                f32x2 p7 = __builtin_amdgcn_cvt_pk_f32_fp8(uB.w, true);
                acc[0]  = fmaf(p0.x, mB, acc[0]);  acc[1]  = fmaf(p0.y, mB, acc[1]);
                acc[2]  = fmaf(p1.x, mB, acc[2]);  acc[3]  = fmaf(p1.y, mB, acc[3]);
                acc[4]  = fmaf(p2.x, mB, acc[4]);  acc[5]  = fmaf(p2.y, mB, acc[5]);
                acc[6]  = fmaf(p3.x, mB, acc[6]);  acc[7]  = fmaf(p3.y, mB, acc[7]);
                acc[8]  = fmaf(p4.x, mB, acc[8]);  acc[9]  = fmaf(p4.y, mB, acc[9]);
                acc[10] = fmaf(p5.x, mB, acc[10]); acc[11] = fmaf(p5.y, mB, acc[11]);
                acc[12] = fmaf(p6.x, mB, acc[12]); acc[13] = fmaf(p6.y, mB, acc[13]);
                acc[14] = fmaf(p7.x, mB, acc[14]); acc[15] = fmaf(p7.y, mB, acc[15]);
            }
        }
        i += cnt;
    }
    // reduce across the 8 edge-groups
#pragma unroll
    for (int j = 0; j < 16; ++j) {
        acc[j] += __shfl_xor(acc[j], 8, 64);
        acc[j] += __shfl_xor(acc[j], 16, 64);
        acc[j] += __shfl_xor(acc[j], 32, 64);
    }
    if (lane < 8) {
        float sc = rs_in[w];
        int base_slot = lane * 16;
        uint32_t o[8];
#pragma unroll
        for (int j = 0; j < 8; ++j) {
            float f0 = fmaxf(fmaf(acc[2 * j], sc, b1[permf(base_slot + 2 * j)]), 0.f);
            float f1 = fmaxf(fmaf(acc[2 * j + 1], sc, b1[permf(base_slot + 2 * j + 1)]), 0.f);
            o[j] = (uint32_t)(unsigned short)f2bf(f0) | ((uint32_t)(unsigned short)f2bf(f1) << 16);
        }
        uint4* dst = (uint4*)(x1b + (size_t)w * 64 + lane * 8);
        dst[0] = make_uint4(o[0], o[1], o[2], o[3]);
        dst[1] = make_uint4(o[4], o[5], o[6], o[7]);
    }
}

// ---------------- GEMM2: h2f = fp8((x1 @ W2) * rs_out[row])  (x1 bf16, column-permuted) ----------------
__global__ __launch_bounds__(256) void k_gemm2(const uint32_t* __restrict__ A, const float* __restrict__ B,
                                               const float* __restrict__ rs_out, unsigned char* __restrict__ h2f,
                                               int M) {
    __shared__ float As[64 * 132];       // [row][k], k-pitch 132
    __shared__ float Wt[OUT_DIM * 132];  // [col][k], k permuted to match x1
    __shared__ unsigned char hs[64 * 40];
    int t = threadIdx.x;
    int base_row = blockIdx.x * 64;
    for (int i = 0; i < 20; ++i) {
        int flat = t + i * 256;          // 5120
        int q = flat / 40, c = flat - q * 40;
        Wt[c * 132 + q] = B[(size_t)permf(q) * OUT_DIM + c];
    }
#pragma unroll
    for (int i = 0; i < 16; ++i) {
        int u = t + i * 256;             // 4096 dword units (2 feats each)
        int row = u >> 6, kc = u & 63;
        int gr = base_row + row;
        uint32_t v = (gr < M) ? A[(size_t)gr * 64 + kc] : 0;
        As[row * 132 + kc * 2] = bf2f((unsigned short)v);
        As[row * 132 + kc * 2 + 1] = bf2f((unsigned short)(v >> 16));
    }
    __syncthreads();
    int cg = t & 7, rg = t >> 3;
    int c0 = cg * 5, r0 = rg * 2;
    float acc[2][5] = {};
    for (int k = 0; k < HID; k += 4) {
        float4 a0 = *(const float4*)&As[r0 * 132 + k];
        float4 a1 = *(const float4*)&As[(r0 + 1) * 132 + k];
#pragma unroll
        for (int j = 0; j < 5; ++j) {
            float4 wv = *(const float4*)&Wt[(c0 + j) * 132 + k];
            acc[0][j] = fmaf(a0.x, wv.x, acc[0][j]);
            acc[0][j] = fmaf(a0.y, wv.y, acc[0][j]);
            acc[0][j] = fmaf(a0.z, wv.z, acc[0][j]);
            acc[0][j] = fmaf(a0.w, wv.w, acc[0][j]);
            acc[1][j] = fmaf(a1.x, wv.x, acc[1][j]);
            acc[1][j] = fmaf(a1.y, wv.y, acc[1][j]);
            acc[1][j] = fmaf(a1.z, wv.z, acc[1][j]);
            acc[1][j] = fmaf(a1.w, wv.w, acc[1][j]);
        }
    }
#pragma unroll
    for (int ri = 0; ri < 2; ++ri) {
        int r = base_row + r0 + ri;
        if (r < M) {
            float sc = rs_out[r];
            float v0 = acc[ri][0] * sc, v1 = acc[ri][1] * sc, v2 = acc[ri][2] * sc;
            float v3 = acc[ri][3] * sc, v4 = acc[ri][4] * sc;
            int p0 = __builtin_amdgcn_cvt_pk_fp8_f32(v0, v1, 0, false);
            int p1 = __builtin_amdgcn_cvt_pk_fp8_f32(v2, v3, 0, false);
            int p2 = __builtin_amdgcn_cvt_pk_fp8_f32(v4, v4, 0, false);
            unsigned char* hp = &hs[(r0 + ri) * 40 + c0];
            hp[0] = (unsigned char)(p0 & 0xff);
            hp[1] = (unsigned char)((p0 >> 8) & 0xff);
            hp[2] = (unsigned char)(p1 & 0xff);
            hp[3] = (unsigned char)((p1 >> 8) & 0xff);
            hp[4] = (unsigned char)(p2 & 0xff);
        }
    }
    __syncthreads();
    int vr = min(64, M - base_row);
    int nd = vr * 10;                    // dwords (40 B rows, contiguous)
    const uint32_t* hw = (const uint32_t*)hs;
    for (int idx = t; idx < nd; idx += 256)
        *(uint32_t*)(h2f + (size_t)base_row * 40 + (size_t)idx * 4) = hw[idx];
}

// ---------------- SpMM2 (fp8, MLP) + bias + log_softmax ----------------
// 5 lanes/edge x uint2 (40 B row); 12 edge-groups/wave; col batch-prefetch via shfl.
__global__ __launch_bounds__(256) void k_spmm2(const unsigned char* __restrict__ h2f, const int* __restrict__ rp,
                                               const int* __restrict__ col, const float* __restrict__ rs_in,
                                               const float* __restrict__ b2, float* __restrict__ out, int n) {
    int w = (blockIdx.x * 256 + threadIdx.x) >> 6;
    int lane = threadIdx.x & 63;
    if (w >= n) return;
    int grp = lane / 5;                  // 0..12 (grp 12 = lanes 60..63, inactive)
    int dw = lane - grp * 5;             // 0..4
    bool gval = grp < 12;
    int s = rp[w], e = rp[w + 1];
    float acc[8] = {};
    int i = s;
    while (i < e) {
        int cnt = min(64, e - i);
        int cl = (lane < cnt) ? lane : cnt - 1;
        int cidx = col[i + cl];
        for (int it = 0; it < cnt; it += 24) {
            int eA = it + grp, eB = it + 12 + grp;
            int cA = __shfl(cidx, eA & 63, 64);
            int cB = __shfl(cidx, eB & 63, 64);
            float mA = (gval && eA < cnt) ? 1.f : 0.f;
            float mB = (gval && eB < cnt) ? 1.f : 0.f;
            uint2 uA = *(const uint2*)(h2f + (size_t)cA * 40 + dw * 8);
            uint2 uB = *(const uint2*)(h2f + (size_t)cB * 40 + dw * 8);
            {
                f32x2 p0 = __builtin_amdgcn_cvt_pk_f32_fp8(uA.x, false);
                f32x2 p1 = __builtin_amdgcn_cvt_pk_f32_fp8(uA.x, true);
                f32x2 p2 = __builtin_amdgcn_cvt_pk_f32_fp8(uA.y, false);
                f32x2 p3 = __builtin_amdgcn_cvt_pk_f32_fp8(uA.y, true);
                acc[0] = fmaf(p0.x, mA, acc[0]); acc[1] = fmaf(p0.y, mA, acc[1]);
                acc[2] = fmaf(p1.x, mA, acc[2]); acc[3] = fmaf(p1.y, mA, acc[3]);
                acc[4] = fmaf(p2.x, mA, acc[4]); acc[5] = fmaf(p2.y, mA, acc[5]);
                acc[6] = fmaf(p3.x, mA, acc[6]); acc[7] = fmaf(p3.y, mA, acc[7]);
            }
            {
                f32x2 p0 = __builtin_amdgcn_cvt_pk_f32_fp8(uB.x, false);
                f32x2 p1 = __builtin_amdgcn_cvt_pk_f32_fp8(uB.x, true);
                f32x2 p2 = __builtin_amdgcn_cvt_pk_f32_fp8(uB.y, false);
                f32x2 p3 = __builtin_amdgcn_cvt_pk_f32_fp8(uB.y, true);
                acc[0] = fmaf(p0.x, mB, acc[0]); acc[1] = fmaf(p0.y, mB, acc[1]);
                acc[2] = fmaf(p1.x, mB, acc[2]); acc[3] = fmaf(p1.y, mB, acc[3]);
                acc[4] = fmaf(p2.x, mB, acc[4]); acc[5] = fmaf(p2.y, mB, acc[5]);
                acc[6] = fmaf(p3.x, mB, acc[6]); acc[7] = fmaf(p3.y, mB, acc[7]);
            }
        }
        i += cnt;
    }
    // fold 12 groups (stride 5) -> group 0 (lanes 0..4)
#pragma unroll
    for (int j = 0; j < 8; ++j) {
        acc[j] += __shfl(acc[j], (lane + 30) & 63, 64);
        acc[j] += __shfl(acc[j], (lane + 15) & 63, 64);
        acc[j] += __shfl(acc[j], (lane + 5) & 63, 64) + __shfl(acc[j], (lane + 10) & 63, 64);
    }
    bool act = lane < 5;
    float sc = rs_in[w];
    float val[8];
#pragma unroll
    for (int j = 0; j < 8; ++j)
        val[j] = fmaf(acc[j], sc, b2[dw * 8 + j]);
    float pm = -INFINITY;
    if (act) {
        pm = val[0];
#pragma unroll
        for (int j = 1; j < 8; ++j) pm = fmaxf(pm, val[j]);
    }
    pm = fmaxf(pm, __shfl_xor(pm, 4, 8));
    pm = fmaxf(pm, __shfl_xor(pm, 2, 8));
    pm = fmaxf(pm, __shfl_xor(pm, 1, 8));
    float ex = 0.f;
    if (act) {
#pragma unroll
        for (int j = 0; j < 8; ++j) ex += expf(val[j] - pm);
    }
    ex += __shfl_xor(ex, 4, 8);
    ex += __shfl_xor(ex, 2, 8);
    ex += __shfl_xor(ex, 1, 8);
    if (act) {
        float l = pm + logf(ex);
        float4 o0 = {val[0] - l, val[1] - l, val[2] - l, val[3] - l};
        float4 o1 = {val[4] - l, val[5] - l, val[6] - l, val[7] - l};
        float* op = out + (size_t)w * OUT_DIM + dw * 8;
        *(float4*)op = o0;
        *(float4*)(op + 4) = o1;
    }
}

// ---------------- launch ----------------

extern "C" void kernel_launch(void* const* d_in, const int* in_sizes, int n_in,
                              void* d_out, int out_size, void* d_ws, size_t ws_size,
                              hipStream_t stream) {
    const int N = in_sizes[0] / IN_DIM;
    const int E = in_sizes[5];
    const float* h  = (const float*)d_in[0];
    const float* W1 = (const float*)d_in[1];
    const float* b1 = (const float*)d_in[2];
    const float* W2 = (const float*)d_in[3];
    const float* b2 = (const float*)d_in[4];
    const int* src  = (const int*)d_in[5];
    const int* dst  = (const int*)d_in[6];
    float* out = (float*)d_out;

    const int NBINS  = (N + BIN_SIZE - 1) >> BIN_SHIFT;   // 98
    const int NCHUNK = (E + CHUNK - 1) / CHUNK;           // 391

    char* w = (char*)d_ws;
    size_t off = 0;
    auto alloc = [&](size_t bytes) -> void* {
        void* p = w + off;
        off += (bytes + 255) & ~(size_t)255;
        return p;
    };
    int* deg_in   = (int*)alloc((size_t)N * 4);
    int* deg_out  = (int*)alloc((size_t)N * 4);
    int* row_ptr  = (int*)alloc((size_t)(N + 1) * 4);
    int* cursor   = (int*)alloc((size_t)N * 4);
    int* bsum     = (int*)alloc(1024 * 4);
    float* rs_out = (float*)alloc((size_t)N * 4);
    float* rs_in  = (float*)alloc((size_t)N * 4);
    int* col      = (int*)alloc((size_t)E * 4);
    int* bboD     = (int*)alloc((size_t)NCHUNK * (NBINS + 1) * 4);
    int* bboS     = (int*)alloc((size_t)NCHUNK * (NBINS + 1) * 4);
    short* Wg     = (short*)alloc((size_t)8 * 8 * 64 * 8 * 2);    // 64 KB
    uint32_t* h1f = (uint32_t*)alloc((size_t)N * HID);            // fp8, 12.8 MB
    unsigned char* h2f = (unsigned char*)alloc((size_t)N * OUT_DIM);  // fp8, 4 MB
    uint32_t* x1b = (uint32_t*)alloc((size_t)N * (HID / 2) * 4);  // bf16 permuted, 25.6 MB
    uint32_t* stD = (uint32_t*)x1b;           // staging dead before spmm1 writes x1b (19.2 <= 25.6 MB)
    unsigned short* stS = (unsigned short*)(x1b + (size_t)E);

    int gN = (N + 255) / 256;
    int NB = (N + 1023) / 1024;

    hipMemsetAsync(deg_in, 0, (size_t)N * 4, stream);
    hipMemsetAsync(deg_out, 0, (size_t)N * 4, stream);
    k_wrepack<<<32, 256, 0, stream>>>(W1, Wg);
    k_binscatter<<<NCHUNK, 256, 0, stream>>>(src, dst, stD, stS, bboD, bboS, E, NBINS);
    k_deg_src<<<dim3(NBINS, GSPLIT), 256, 0, stream>>>(stS, bboS, deg_out, N, NCHUNK, NBINS);
    k_deg_dst<<<dim3(NBINS, GSPLIT), 256, 0, stream>>>(stD, bboD, deg_in, N, NCHUNK, NBINS);
    k_scan1<<<NB, 256, 0, stream>>>(deg_in, row_ptr, bsum, rs_in, N);
    k_scan2<<<1, 1024, 0, stream>>>(bsum, NB);
    k_scan3<<<gN, 256, 0, stream>>>(row_ptr, bsum, cursor, deg_out, rs_out, N, E);
    k_col<<<dim3(NBINS, GSPLIT), 256, 0, stream>>>(stD, bboD, cursor, col, N, NCHUNK, NBINS);
    k_gemm1<<<(N + 63) / 64, 256, 0, stream>>>(h, Wg, rs_out, h1f, N);
    k_spmm1<<<(N + 3) / 4, 256, 0, stream>>>((const uint4*)h1f, row_ptr, col, rs_in, b1, x1b, N);
    k_gemm2<<<(N + 63) / 64, 256, 0, stream>>>(x1b, W2, rs_out, h2f, N);
    k_spmm2<<<(N + 3) / 4, 256, 0, stream>>>(h2f, row_ptr, col, rs_in, b2, out, N);
}